// Round 7
// baseline (1643.598 us; speedup 1.0000x reference)
//
#include <hip/hip_runtime.h>
#include <hip/hip_bf16.h>
#include <math.h>

// ---------------------------------------------------------------------------
// helpers
// ---------------------------------------------------------------------------
typedef __bf16 v8bf __attribute__((ext_vector_type(8)));
typedef float  v4f  __attribute__((ext_vector_type(4)));
typedef unsigned short v8us __attribute__((ext_vector_type(8)));

__device__ __forceinline__ unsigned short f2bfu(float f) {
    unsigned u = __builtin_bit_cast(unsigned, f);
    unsigned r = (u + 0x7fffu + ((u >> 16) & 1u)) >> 16;
    return (unsigned short)r;
}
__device__ __forceinline__ float bf2f(unsigned short u) {
    unsigned x = ((unsigned)u) << 16;
    return __builtin_bit_cast(float, x);
}

// fragment-swizzled element address: matrix [rows][K cols] stored so that a
// wave's 16x32 MFMA fragment is contiguous: sw(r,k) =
//   tile(r>>4, k>>5) * 512 + lane((k>>3)&3, r&15) * 8 + (k&7)
__device__ __forceinline__ long long swidx(int r, int k, int kt /*=K>>5*/) {
    return ((long long)((r >> 4) * kt + (k >> 5)) << 9)
         + (((k >> 3) & 3) << 7) + ((r & 15) << 3) + (k & 7);
}

#define GLDS16(g, s)                                                        \
    __builtin_amdgcn_global_load_lds(                                       \
        (const __attribute__((address_space(1))) void*)(g),                 \
        (__attribute__((address_space(3))) void*)(s), 16, 0, 0)

// ---------------------------------------------------------------------------
// SWIZZLED register-direct bf16 MFMA GEMM (no LDS, no barriers).
// A (M x K) and B (N x K) in fragment-swizzled layout (see swidx).
// ONE WAVE PER BLOCK (64 threads), wave tile 64(M) x 128(N).
//
// R1-R6 post-mortem (the law of this session): the toolchain will NOT hold
// a multi-chunk register pipeline — six structurally different rings
// (copy-back, branch-free, sched_barrier-pinned, inline-asm + counted
// vmcnt) all collapsed to ~1 chunk in flight (VGPR 80/96/108/116, MfmaUtil
// 16-19%, one ~400cy round-trip per chunk). So optimize the COLLAPSED
// schedule: per-chunk time ~= L + t_mfma; raise t_mfma per loaded byte.
// 64x128 tile: 12 KB/chunk (A 4 + B 8 frags) feeds 32 MFMAs (~160cy) vs
// the old 64x64's 8KB/16 MFMA (~80cy) -> per-wave duty ~26% vs 17%, and
// 2x FLOPs per chunk. Single-buffered, branch-free, no copies — maximally
// simple; VGPR = 128 acc + 48 buf + ~25 addr ≈ 200 < 256 @ (64,2).
//
// Outputs: Cf (fp32,+res row-major) | Cb (bf16 row-major) | Csw (bf16
// swizzled for the next GEMM, K_consumer = N) ; cols >= ctcol0 (Ct!=null)
// go transposed to Ct (attention V^T). M mult of 64, N mult of 128,
// K mult of 32.
// ---------------------------------------------------------------------------
__global__ __launch_bounds__(64, 2) void gemm_sw_k(
    const unsigned short* __restrict__ Asw,
    const unsigned short* __restrict__ Bsw,
    const float* __restrict__ bias,
    const float* __restrict__ res,
    float* __restrict__ Cf,
    unsigned short* __restrict__ Cb,
    unsigned short* __restrict__ Csw,
    unsigned short* __restrict__ Ct, int ctcol0,
    int M, int N, int K, int ldC, int relu)
{
    const int l = threadIdx.x;

    int bx = blockIdx.x, by = blockIdx.y;
    {
        int nbx = gridDim.x;
        int nb  = nbx * gridDim.y;
        if ((nb & 7) == 0) {
            int bid = by * nbx + bx;
            int nid = (bid & 7) * (nb >> 3) + (bid >> 3);
            by = nid / nbx;
            bx = nid - by * nbx;
        }
    }
    const int m0 = by * 64;
    const int n0 = bx * 128;
    const int r16 = l & 15;
    const int qb  = l >> 4;
    const int kt = K >> 5;

    // fragment base pointers: contiguous 16B per lane
    const unsigned short* pa[4];
#pragma unroll
    for (int i = 0; i < 4; i++)
        pa[i] = Asw + ((long long)(((m0 >> 4) + i) * kt) << 9) + l * 8;
    const unsigned short* pb[8];
#pragma unroll
    for (int j = 0; j < 8; j++)
        pb[j] = Bsw + ((long long)(((n0 >> 4) + j) * kt) << 9) + l * 8;

    v4f acc[4][8];
#pragma unroll
    for (int i = 0; i < 4; i++)
#pragma unroll
        for (int j = 0; j < 8; j++) acc[i][j] = (v4f){0.f, 0.f, 0.f, 0.f};

    for (int c = 0; c < kt; ++c) {
        const long long o = (long long)c << 9;
        v8bf av[4], bfv[8];
#pragma unroll
        for (int i = 0; i < 4; i++) av[i] = *(const v8bf*)(pa[i] + o);
#pragma unroll
        for (int j = 0; j < 8; j++) bfv[j] = *(const v8bf*)(pb[j] + o);
#pragma unroll
        for (int i = 0; i < 4; i++)
#pragma unroll
            for (int j = 0; j < 8; j++)
                acc[i][j] = __builtin_amdgcn_mfma_f32_16x16x32_bf16(
                    av[i], bfv[j], acc[i][j], 0, 0, 0);
    }

    float bv[8];
#pragma unroll
    for (int j = 0; j < 8; j++) bv[j] = bias[n0 + 16 * j + r16];
    const int colbase = n0 + r16;
    const int nt = N >> 5;
#pragma unroll
    for (int i = 0; i < 4; i++) {
        int rowb = m0 + 16 * i + qb * 4;
#pragma unroll
        for (int j = 0; j < 8; j++) {
            int col = colbase + 16 * j;
            float v[4];
#pragma unroll
            for (int r = 0; r < 4; r++) v[r] = acc[i][j][r] + bv[j];
            if (Ct && col >= ctcol0) {
                ushort4 o;
                o.x = f2bfu(v[0]); o.y = f2bfu(v[1]);
                o.z = f2bfu(v[2]); o.w = f2bfu(v[3]);
                *(ushort4*)(Ct + ((long long)(rowb >> 10) << 20)
                            + (long long)(col - ctcol0) * 1024 + (rowb & 1023)) = o;
            } else if (Csw) {
#pragma unroll
                for (int r = 0; r < 4; r++) {
                    int row = rowb + r;
                    float vv = v[r];
                    if (relu) vv = fmaxf(vv, 0.f);
                    Csw[swidx(row, col, nt)] = f2bfu(vv);
                }
            } else {
#pragma unroll
                for (int r = 0; r < 4; r++) {
                    int row = rowb + r;
                    long long off = (long long)row * ldC + col;
                    float vv = v[r];
                    if (res)  vv += res[off];
                    if (relu) vv = fmaxf(vv, 0.f);
                    if (Cf) Cf[off] = vv;
                    if (Cb) ((unsigned short*)Cb)[off] = f2bfu(vv);
                }
            }
        }
    }
}

// ---------------------------------------------------------------------------
// LDS-staged GEMM (R5) — kept for the conv frontend (row-remapped A).
// ---------------------------------------------------------------------------
__global__ __launch_bounds__(256) void gemm_mfma_k(
    const __hip_bfloat16* __restrict__ A, int rpbA, long long bstrideA, int ldA,
    const __hip_bfloat16* __restrict__ B,
    const float* __restrict__ bias,
    const float* __restrict__ res,
    float* __restrict__ Cf,
    __hip_bfloat16* __restrict__ Cb,
    int M, int N, int K, int ldC, int relu)
{
    __shared__ __align__(16) __hip_bfloat16 As[2][8][64][8];
    __shared__ __align__(16) __hip_bfloat16 Bs[2][4][64][8];
    const int t  = threadIdx.x;
    const int w  = t >> 6;
    const int l  = t & 63;
    const int m0 = blockIdx.y * 128;
    const int n0 = blockIdx.x * 64;
    const int r16 = l & 15;
    const int qb  = l >> 4;
    const int wm = w >> 1, wn = w & 1;

    const __hip_bfloat16* gA[2];
#pragma unroll
    for (int tt = 0; tt < 2; tt++) {
        int arow = m0 + 16 * (2 * w + tt) + r16;
        gA[tt] = A + (long long)(arow / rpbA) * bstrideA
                   + (long long)(arow % rpbA) * ldA + qb * 8;
    }
    const __hip_bfloat16* gB = B + (long long)(n0 + 16 * w + r16) * K + qb * 8;

    v4f acc[4][2];
#pragma unroll
    for (int i = 0; i < 4; i++)
#pragma unroll
        for (int j = 0; j < 2; j++) acc[i][j] = (v4f){0.f, 0.f, 0.f, 0.f};

    GLDS16(gA[0], &As[0][2 * w + 0][0][0]);
    GLDS16(gA[1], &As[0][2 * w + 1][0][0]);
    GLDS16(gB,    &Bs[0][w][0][0]);
    __syncthreads();

    int cur = 0;
    for (int k0 = 32; k0 < K; k0 += 32) {
        v8bf af[4], bfr[2];
#pragma unroll
        for (int i = 0; i < 4; i++) af[i]  = *(const v8bf*)(&As[cur][4 * wm + i][l][0]);
#pragma unroll
        for (int j = 0; j < 2; j++) bfr[j] = *(const v8bf*)(&Bs[cur][2 * wn + j][l][0]);
        GLDS16(gA[0] + k0, &As[cur ^ 1][2 * w + 0][0][0]);
        GLDS16(gA[1] + k0, &As[cur ^ 1][2 * w + 1][0][0]);
        GLDS16(gB + k0,    &Bs[cur ^ 1][w][0][0]);
#pragma unroll
        for (int i = 0; i < 4; i++)
#pragma unroll
            for (int j = 0; j < 2; j++)
                acc[i][j] = __builtin_amdgcn_mfma_f32_16x16x32_bf16(
                    af[i], bfr[j], acc[i][j], 0, 0, 0);
        __syncthreads();
        cur ^= 1;
    }
    {
        v8bf af[4], bfr[2];
#pragma unroll
        for (int i = 0; i < 4; i++) af[i]  = *(const v8bf*)(&As[cur][4 * wm + i][l][0]);
#pragma unroll
        for (int j = 0; j < 2; j++) bfr[j] = *(const v8bf*)(&Bs[cur][2 * wn + j][l][0]);
#pragma unroll
        for (int i = 0; i < 4; i++)
#pragma unroll
            for (int j = 0; j < 2; j++)
                acc[i][j] = __builtin_amdgcn_mfma_f32_16x16x32_bf16(
                    af[i], bfr[j], acc[i][j], 0, 0, 0);
    }

    float bv[2];
#pragma unroll
    for (int j = 0; j < 2; j++) bv[j] = bias[n0 + 32 * wn + 16 * j + r16];
    const int colbase = n0 + 32 * wn + r16;
#pragma unroll
    for (int i = 0; i < 4; i++) {
        int rowb = m0 + 64 * wm + 16 * i + qb * 4;
#pragma unroll
        for (int j = 0; j < 2; j++) {
            int col = colbase + 16 * j;
#pragma unroll
            for (int r = 0; r < 4; r++) {
                int row = rowb + r;
                if (row >= M) continue;
                long long off = (long long)row * ldC + col;
                float vv = acc[i][j][r] + bv[j];
                if (res)  vv += res[off];
                if (relu) vv = fmaxf(vv, 0.f);
                if (Cf) Cf[off] = vv;
                if (Cb) ((unsigned short*)Cb)[off] = f2bfu(vv);
            }
        }
    }
}

// ---------------------------------------------------------------------------
// MFMA softsign attention. Output written in SWIZZLED layout (K=1024 -> 32).
// ---------------------------------------------------------------------------
__global__ __launch_bounds__(256) void attn_mfma_k(
    const unsigned short* __restrict__ QKV,
    const unsigned short* __restrict__ Vt,
    unsigned short* __restrict__ Osw)
{
    __shared__ __align__(16) unsigned short lds[25600];
    const int t = threadIdx.x, w = t >> 6, l = t & 63;
    const int bh = blockIdx.y, b = bh >> 4, h = bh & 15;
    const int s0 = blockIdx.x << 7;
    const int r16 = l & 15, q4 = l >> 4;
    const long long qrow0 = (long long)(b << 10) + s0;
    const int hoff = h << 6;

#pragma unroll
    for (int mi = 0; mi < 2; mi++)
#pragma unroll
        for (int kk = 0; kk < 2; kk++) {
            const unsigned short* g = QKV + (qrow0 + 32 * w + 16 * mi + r16) * 3072
                                      + hoff + 32 * kk + q4 * 8;
            GLDS16(g, &lds[(w * 4 + mi * 2 + kk) * 512]);
        }
    __syncthreads();
    v8bf qf[2][2];
#pragma unroll
    for (int mi = 0; mi < 2; mi++)
#pragma unroll
        for (int kk = 0; kk < 2; kk++)
            qf[mi][kk] = *(const v8bf*)&lds[(w * 4 + mi * 2 + kk) * 512 + l * 8];

    v4f oacc[2][4];
#pragma unroll
    for (int i = 0; i < 2; i++)
#pragma unroll
        for (int j = 0; j < 4; j++) oacc[i][j] = (v4f){0.f, 0.f, 0.f, 0.f};

    for (int t0 = 0; t0 < 1024; t0 += 64) {
#pragma unroll
        for (int rr = 0; rr < 2; rr++) {
            int r = 2 * w + rr, kk = r >> 2, j = r & 3;
            const unsigned short* gk = QKV
                + ((long long)(b << 10) + t0 + 16 * j + r16) * 3072
                + 1024 + hoff + 32 * kk + q4 * 8;
            GLDS16(gk, &lds[8192 + r * 512]);
            const unsigned short* gv = Vt + ((long long)b << 20)
                + (long long)(hoff + 16 * j + r16) * 1024 + t0 + 32 * kk + q4 * 8;
            GLDS16(gv, &lds[12288 + r * 512]);
        }
        __syncthreads();

        v8bf kf[2][4];
#pragma unroll
        for (int kk = 0; kk < 2; kk++)
#pragma unroll
            for (int j = 0; j < 4; j++)
                kf[kk][j] = *(const v8bf*)&lds[8192 + (kk * 4 + j) * 512 + l * 8];
        v4f sc[2][4];
#pragma unroll
        for (int i = 0; i < 2; i++)
#pragma unroll
            for (int j = 0; j < 4; j++) sc[i][j] = (v4f){0.f, 0.f, 0.f, 0.f};
#pragma unroll
        for (int kk = 0; kk < 2; kk++)
#pragma unroll
            for (int mi = 0; mi < 2; mi++)
#pragma unroll
                for (int j = 0; j < 4; j++)
                    sc[mi][j] = __builtin_amdgcn_mfma_f32_16x16x32_bf16(
                        qf[mi][kk], kf[kk][j], sc[mi][j], 0, 0, 0);

#pragma unroll
        for (int mi = 0; mi < 2; mi++)
#pragma unroll
            for (int j = 0; j < 4; j++)
#pragma unroll
                for (int r = 0; r < 4; r++) {
                    float v = sc[mi][j][r] * 0.125f;
                    float p = v * __builtin_amdgcn_rcpf(1.0f + fabsf(v));
                    lds[16384 + (32 * w + 16 * mi + q4 * 4 + r) * 72 + 16 * j + r16] = f2bfu(p);
                }

        v8bf pf[2][2], vf[2][4];
#pragma unroll
        for (int mi = 0; mi < 2; mi++)
#pragma unroll
            for (int kk = 0; kk < 2; kk++)
                pf[mi][kk] = *(const v8bf*)&lds[16384 + (32 * w + 16 * mi + r16) * 72
                                                + 32 * kk + q4 * 8];
#pragma unroll
        for (int kk = 0; kk < 2; kk++)
#pragma unroll
            for (int j = 0; j < 4; j++)
                vf[kk][j] = *(const v8bf*)&lds[12288 + (kk * 4 + j) * 512 + l * 8];
#pragma unroll
        for (int kk = 0; kk < 2; kk++)
#pragma unroll
            for (int mi = 0; mi < 2; mi++)
#pragma unroll
                for (int j = 0; j < 4; j++)
                    oacc[mi][j] = __builtin_amdgcn_mfma_f32_16x16x32_bf16(
                        pf[mi][kk], vf[kk][j], oacc[mi][j], 0, 0, 0);
        __syncthreads();
    }

#pragma unroll
    for (int mi = 0; mi < 2; mi++)
#pragma unroll
        for (int j = 0; j < 4; j++)
#pragma unroll
            for (int r = 0; r < 4; r++)
                lds[(32 * w + 16 * mi + q4 * 4 + r) * 72 + 16 * j + r16] =
                    f2bfu(oacc[mi][j][r]);
    __syncthreads();
    {
        int row = t >> 1, ch = (t & 1) << 5;
        int grow = (int)qrow0 + row;
#pragma unroll
        for (int i = 0; i < 4; i++) {
            int c0 = hoff + ch + 8 * i;
            v8us vv = *(const v8us*)&lds[row * 72 + ch + 8 * i];
            *(v8us*)(Osw + swidx(grow, c0, 32)) = vv;
        }
    }
}

// ---------------------------------------------------------------------------
// LayerNorm (torch-style), output bf16 in SWIZZLED layout (K=1024).
// ---------------------------------------------------------------------------
__global__ __launch_bounds__(256) void layernorm_k(
    const float* __restrict__ x, const float* __restrict__ w,
    const float* __restrict__ b, unsigned short* __restrict__ ysw)
{
    int row = blockIdx.x;
    int t = threadIdx.x;
    float4 v = ((const float4*)(x + ((long long)row << 10)))[t];
    float s = v.x + v.y + v.z + v.w;
#pragma unroll
    for (int o = 32; o; o >>= 1) s += __shfl_down(s, o);
    __shared__ float red[4];
    __shared__ float red2[4];
    int wid = t >> 6, lane = t & 63;
    if (lane == 0) red[wid] = s;
    __syncthreads();
    float mean = (red[0] + red[1] + red[2] + red[3]) * (1.0f / 1024.0f);
    float dx = v.x - mean, dy = v.y - mean, dz = v.z - mean, dw = v.w - mean;
    float sq = dx * dx + dy * dy + dz * dz + dw * dw;
#pragma unroll
    for (int o = 32; o; o >>= 1) sq += __shfl_down(sq, o);
    if (lane == 0) red2[wid] = sq;
    __syncthreads();
    float var = (red2[0] + red2[1] + red2[2] + red2[3]) * (1.0f / 1023.0f);
    float inv = 1.0f / (sqrtf(var) + 1e-6f);
    float4 W  = ((const float4*)w)[t];
    float4 Bv = ((const float4*)b)[t];
    ushort4 o;
    o.x = f2bfu(W.x * (dx * inv) + Bv.x);
    o.y = f2bfu(W.y * (dy * inv) + Bv.y);
    o.z = f2bfu(W.z * (dz * inv) + Bv.z);
    o.w = f2bfu(W.w * (dw * inv) + Bv.w);
    int c0 = t << 2;
    *(ushort4*)(ysw + swidx(row, c0, 32)) = o;
}

// ---------------------------------------------------------------------------
__global__ __launch_bounds__(256) void add_pos_k(float* __restrict__ h)
{
    int idx = blockIdx.x * 256 + threadIdx.x;
    int d = idx & 1023;
    int s = (idx >> 10) & 1023;
    int e = d & ~1;
    float div = expf(-9.210340371976184f * (float)e * (1.0f / 1024.0f));
    float arg = (float)s * div;
    float pe = (d & 1) ? cosf(arg) : sinf(arg);
    h[idx] += pe;
}

__global__ __launch_bounds__(256) void convert_k(
    const float* __restrict__ src, unsigned short* __restrict__ dst, int n4)
{
    int i = blockIdx.x * 256 + threadIdx.x;
    if (i >= n4) return;
    float4 v = ((const float4*)src)[i];
    ushort4 o;
    o.x = f2bfu(v.x); o.y = f2bfu(v.y); o.z = f2bfu(v.z); o.w = f2bfu(v.w);
    ((ushort4*)dst)[i] = o;
}

// Layer weights fp32 row-major -> bf16 SWIZZLED, all 6 matrices, one launch.
// dst layout (us): q,k,v,o (1M each), f1 (2M), f2 (2M) — contiguous.
__global__ __launch_bounds__(256) void convert_layer_sw_k(
    const float* __restrict__ q, const float* __restrict__ k,
    const float* __restrict__ v, const float* __restrict__ o,
    const float* __restrict__ f1, const float* __restrict__ f2,
    unsigned short* __restrict__ dst)
{
    int idx = blockIdx.x * 256 + threadIdx.x;   // float4 index, [0, 2M)
    const float* src;
    unsigned short* db;
    int Ksh, rf;
    if (idx < 0x100000) {
        int region = idx >> 18;
        rf = idx & 0x3FFFF;
        src = (region == 0) ? q : (region == 1) ? k : (region == 2) ? v : o;
        db = dst + ((long long)region << 20);
        Ksh = 10;
    } else if (idx < 0x180000) {
        rf = idx - 0x100000; src = f1; db = dst + (4LL << 20); Ksh = 10;
    } else {
        rf = idx - 0x180000; src = f2; db = dst + (6LL << 20); Ksh = 11;
    }
    float4 vv = ((const float4*)src)[rf];
    int flatf = rf << 2;
    int n  = flatf >> Ksh;
    int k0 = flatf & ((1 << Ksh) - 1);
    ushort4 ov;
    ov.x = f2bfu(vv.x); ov.y = f2bfu(vv.y); ov.z = f2bfu(vv.z); ov.w = f2bfu(vv.w);
    *(ushort4*)(db + swidx(n, k0, 1 << (Ksh - 5))) = ov;
}

__global__ __launch_bounds__(256) void concat3_k(
    const float* __restrict__ a, const float* __restrict__ b,
    const float* __restrict__ c, float* __restrict__ o)
{
    int i = blockIdx.x * 256 + threadIdx.x;
    o[i] = (i < 1024) ? a[i] : ((i < 2048) ? b[i - 1024] : c[i - 2048]);
}

__global__ __launch_bounds__(256) void reorder_w_k(
    const float* __restrict__ src, unsigned short* __restrict__ dst, int OC, int IC)
{
    int idx = blockIdx.x * 256 + threadIdx.x;
    if (idx >= OC * IC * 3) return;
    int k  = idx % 3;
    int ic = (idx / 3) % IC;
    int oc = idx / (3 * IC);
    dst[(oc * 3 + k) * IC + ic] = f2bfu(src[idx]);
}

// meanpool split: 256-block partial pass (16 rows each, all 1024 d) then a
// 16-block reduce. Old single-pass version ran on only 16 CUs pulling 16 MB.
__global__ __launch_bounds__(256) void meanpool_part_k(
    const float* __restrict__ h, float* __restrict__ part)
{
    int g = blockIdx.x;                 // g = b*64 + rblk
    int b = g >> 6, rblk = g & 63;
    const float4* base = (const float4*)(h + ((long long)b << 20)
                                           + ((long long)(rblk * 16) << 10));
    float4 s = {0.f, 0.f, 0.f, 0.f};
#pragma unroll
    for (int i = 0; i < 16; i++) {
        float4 v = base[i * 256 + threadIdx.x];
        s.x += v.x; s.y += v.y; s.z += v.z; s.w += v.w;
    }
    ((float4*)part)[g * 256 + threadIdx.x] = s;
}

__global__ __launch_bounds__(256) void meanpool_red_k(
    const float* __restrict__ part, float* __restrict__ pooled)
{
    int idx = blockIdx.x * 256 + threadIdx.x;   // 4096: b = idx>>10, d = idx&1023
    int b = idx >> 10, d = idx & 1023;
    const float* p = part + ((long long)(b * 64) << 10) + d;
    float s = 0.f;
#pragma unroll 8
    for (int r = 0; r < 64; r++) s += p[r << 10];
    pooled[idx] = s * (1.0f / 1024.0f);
}

__global__ __launch_bounds__(256) void fc_k(
    const float* __restrict__ p, const float* __restrict__ w,
    const float* __restrict__ fb, float* __restrict__ out)
{
    int b = blockIdx.x, t = threadIdx.x;
    float s = 0.f;
    for (int i = t; i < 1024; i += 256) s += p[(b << 10) + i] * w[i];
#pragma unroll
    for (int o = 32; o; o >>= 1) s += __shfl_down(s, o);
    __shared__ float red[4];
    if ((t & 63) == 0) red[t >> 6] = s;
    __syncthreads();
    if (t == 0) out[b] = red[0] + red[1] + red[2] + red[3] + fb[0];
}

// ---------------------------------------------------------------------------
extern "C" void kernel_launch(void* const* d_in, const int* in_sizes, int n_in,
                              void* d_out, int out_size, void* d_ws, size_t ws_size,
                              hipStream_t stream)
{
    const float* x    = (const float*)d_in[0];
    const float* c1w  = (const float*)d_in[1];
    const float* c1b  = (const float*)d_in[2];
    const float* c2w  = (const float*)d_in[3];
    const float* c2b  = (const float*)d_in[4];
    const float* lnAw = (const float*)d_in[5];
    const float* lnAb = (const float*)d_in[6];
    const float* qw   = (const float*)d_in[7];
    const float* qbi  = (const float*)d_in[8];
    const float* kw   = (const float*)d_in[9];
    const float* kbi  = (const float*)d_in[10];
    const float* vw   = (const float*)d_in[11];
    const float* vbi  = (const float*)d_in[12];
    const float* ow   = (const float*)d_in[13];
    const float* obi  = (const float*)d_in[14];
    const float* lnBw = (const float*)d_in[15];
    const float* lnBb = (const float*)d_in[16];
    const float* f1w  = (const float*)d_in[17];
    const float* f1b  = (const float*)d_in[18];
    const float* f2w  = (const float*)d_in[19];
    const float* f2b  = (const float*)d_in[20];
    const float* fcw  = (const float*)d_in[21];
    const float* fcb  = (const float*)d_in[22];
    float* out = (float*)d_out;

    float* ws = (float*)d_ws;
    typedef __hip_bfloat16 bf;
    typedef unsigned short us;
    float* h    = ws;                          // 4,194,304 f
    us* hn_b    = (us*)(ws + 4194304);         // 4M us (swizzled activations)
    us* qkv_b   = (us*)(ws + 6291456);         // [4096][3072] us row-major
    us* ff_b    = qkv_b;                       // [4096][2048] swizzled overlay
    us* wq_b    = (us*)(ws + 12582912);        // swizzled: q,k,v,o,f1,f2
    us* wo_b    = (us*)(ws + 14155776);
    us* wf1_b   = (us*)(ws + 14680064);
    us* wf2_b   = (us*)(ws + 15728640);
    us* xb      = (us*)(ws + 16777216);
    us* h1b     = (us*)(ws + 16912896);
    us* w1t_b   = (us*)(ws + 17963520);
    us* w2t_b   = (us*)(ws + 18012672);
    float* pooled = ws + 18799104;             // 4,096 f
    us* Vt      = (us*)(ws + 18803200);        // [4][1024 d][1024 t] us
    float* bqkv = ws + 20900352;               // 3,072 f
    float* mp_part = ws + 20903424;            // 262,144 f (meanpool partials)

    convert_k<<<dim3(257), 256, 0, stream>>>(x, xb, 65792);
    reorder_w_k<<<dim3(384),  256, 0, stream>>>(c1w, w1t_b, 512, 64);
    reorder_w_k<<<dim3(6144), 256, 0, stream>>>(c2w, w2t_b, 1024, 512);

    // conv1: M=4104, N=512, K=192 (LDS-staged kernel, row-remapped A)
    gemm_mfma_k<<<dim3(8, 33), 256, 0, stream>>>(
        (const bf*)xb, 1026, 1028LL * 64, 64, (const bf*)w1t_b,
        c1b, nullptr, nullptr, (bf*)h1b, 4104, 512, 192, 512, 0);
    // conv2: M=4096, N=1024, K=1536
    gemm_mfma_k<<<dim3(16, 32), 256, 0, stream>>>(
        (const bf*)h1b, 1024, 1026LL * 512, 512, (const bf*)w2t_b,
        c2b, nullptr, h, nullptr, 4096, 1024, 1536, 1024, 0);
    add_pos_k<<<dim3(16384), 256, 0, stream>>>(h);

    for (int l = 0; l < 4; l++) {
        long long wo  = (long long)l * 1048576;
        long long wo2 = (long long)l * 2097152;
        convert_layer_sw_k<<<dim3(8192), 256, 0, stream>>>(
            qw + wo, kw + wo, vw + wo, ow + wo, f1w + wo2, f2w + wo2, wq_b);
        concat3_k<<<dim3(12), 256, 0, stream>>>(qbi + l * 1024, kbi + l * 1024,
                                                vbi + l * 1024, bqkv);

        layernorm_k<<<dim3(4096), 256, 0, stream>>>(h, lnAw + l * 1024, lnAb + l * 1024, hn_b);
        // fused QKV: N=3072; Q,K swizzled to qkv_b; V transposed to Vt
        gemm_sw_k<<<dim3(24, 64), 64, 0, stream>>>(
            hn_b, wq_b, bqkv, nullptr, nullptr, qkv_b, nullptr, Vt, 2048,
            4096, 3072, 1024, 3072, 0);
        attn_mfma_k<<<dim3(8, 64), 256, 0, stream>>>(qkv_b, Vt, hn_b);
        // O-proj: out fp32 h += res
        gemm_sw_k<<<dim3(8, 64), 64, 0, stream>>>(
            hn_b, wo_b, obi + l * 1024, h, h, nullptr, nullptr, nullptr, 0,
            4096, 1024, 1024, 1024, 0);
        layernorm_k<<<dim3(4096), 256, 0, stream>>>(h, lnBw + l * 1024, lnBb + l * 1024, hn_b);
        // FF1: out swizzled bf16 (+relu)
        gemm_sw_k<<<dim3(16, 64), 64, 0, stream>>>(
            hn_b, wf1_b, f1b + l * 2048, nullptr, nullptr, nullptr, ff_b, nullptr, 0,
            4096, 2048, 1024, 2048, 1);
        // FF2: out fp32 h += res
        gemm_sw_k<<<dim3(8, 64), 64, 0, stream>>>(
            ff_b, wf2_b, f2b + l * 1024, h, h, nullptr, nullptr, nullptr, 0,
            4096, 1024, 2048, 1024, 0);
    }

    meanpool_part_k<<<dim3(256), 256, 0, stream>>>(h, mp_part);
    meanpool_red_k<<<dim3(16), 256, 0, stream>>>(mp_part, pooled);
    fc_k<<<dim3(4), 256, 0, stream>>>(pooled, fcw, fcb, out);
}

// Round 8
// 1268.503 us; speedup vs baseline: 1.2957x; 1.2957x over previous
//
#include <hip/hip_runtime.h>
#include <hip/hip_bf16.h>
#include <math.h>

// ---------------------------------------------------------------------------
// helpers
// ---------------------------------------------------------------------------
typedef __bf16 v8bf __attribute__((ext_vector_type(8)));
typedef float  v4f  __attribute__((ext_vector_type(4)));
typedef unsigned short v8us __attribute__((ext_vector_type(8)));

__device__ __forceinline__ unsigned short f2bfu(float f) {
    unsigned u = __builtin_bit_cast(unsigned, f);
    unsigned r = (u + 0x7fffu + ((u >> 16) & 1u)) >> 16;
    return (unsigned short)r;
}
__device__ __forceinline__ float bf2f(unsigned short u) {
    unsigned x = ((unsigned)u) << 16;
    return __builtin_bit_cast(float, x);
}

// fragment-swizzled element address: matrix [rows][K cols] stored so that a
// wave's 16x32 MFMA fragment is contiguous: sw(r,k) =
//   tile(r>>4, k>>5) * 512 + lane((k>>3)&3, r&15) * 8 + (k&7)
__device__ __forceinline__ long long swidx(int r, int k, int kt /*=K>>5*/) {
    return ((long long)((r >> 4) * kt + (k >> 5)) << 9)
         + (((k >> 3) & 3) << 7) + ((r & 15) << 3) + (k & 7);
}

#define GLDS16(g, s)                                                        \
    __builtin_amdgcn_global_load_lds(                                       \
        (const __attribute__((address_space(1))) void*)(g),                 \
        (__attribute__((address_space(3))) void*)(s), 16, 0, 0)

// ---------------------------------------------------------------------------
// SWIZZLED bf16 MFMA GEMM, 128x128 tile, DEPTH-4 LDS ring with COUNTED
// vmcnt + raw s_barrier (T3/T4, the guide's verified mechanism m218/m201).
//
// Session law (R1-R7): register rings collapse to 1 chunk in flight
// (~490 TF plateau); bigger register tiles spill (R7: VGPR=88, acc in
// scratch, 6% MfmaUtil); __syncthreads-based LDS staging dies at our
// shapes because it lowers with a vmcnt(0) drain at 1-2 blocks/CU (R2).
// This kernel keeps R2's proven-correct data paths (fragment-contiguous
// LDS staging via global_load_lds, zero bank conflicts) and changes ONLY
// the sync: 4-buffer LDS ring (64 KB), prefetch distance 3; each wave
// issues 4 GLDS/chunk so 12 stay outstanding; s_waitcnt vmcnt(12) retires
// exactly the chunk about to be consumed (FIFO); raw asm s_barrier does
// NOT drain the counter, so prefetches remain in flight across barriers.
// Two barriers/chunk: (1) after wait -> all waves' chunk-c frags visible
// (RAW); (2) after MFMA -> all waves done reading buf[c&3] before anyone
// stages chunk c+4 into it (WAR). Tail peels 3 chunks: vmcnt(8/4/0).
//
// Outputs: Cf (fp32,+res row-major) | Cb (bf16 row-major) | Csw (bf16
// swizzled for the next GEMM, K_consumer = N) ; cols >= ctcol0 (Ct!=null)
// go transposed to Ct (attention V^T). M,N multiples of 128; kt=K/32 >= 4.
// ---------------------------------------------------------------------------
#define BARRIER() asm volatile("s_barrier" ::: "memory")
#define WAITC(n) do {                                                       \
    asm volatile("s_waitcnt vmcnt(" #n ")" ::: "memory");                   \
    __builtin_amdgcn_sched_barrier(0);                                      \
} while (0)

__global__ __launch_bounds__(256) void gemm_sw_k(
    const unsigned short* __restrict__ Asw,
    const unsigned short* __restrict__ Bsw,
    const float* __restrict__ bias,
    const float* __restrict__ res,
    float* __restrict__ Cf,
    unsigned short* __restrict__ Cb,
    unsigned short* __restrict__ Csw,
    unsigned short* __restrict__ Ct, int ctcol0,
    int M, int N, int K, int ldC, int relu)
{
    __shared__ __align__(16) unsigned short As[4][8][512];
    __shared__ __align__(16) unsigned short Bs[4][8][512];
    const int t = threadIdx.x;
    const int w = t >> 6;
    const int l = t & 63;

    int bx = blockIdx.x, by = blockIdx.y;
    {
        int nbx = gridDim.x;
        int nb  = nbx * gridDim.y;
        if ((nb & 7) == 0) {
            int bid = by * nbx + bx;
            int nid = (bid & 7) * (nb >> 3) + (bid >> 3);
            by = nid / nbx;
            bx = nid - by * nbx;
        }
    }
    const int m0 = by * 128;
    const int n0 = bx * 128;
    const int r16 = l & 15;
    const int qb  = l >> 4;
    const int wm = w >> 1, wn = w & 1;
    const int kt = K >> 5;

    // staging sources: wave w stages A row-tiles {2w,2w+1}, B col-tiles {2w,2w+1}
    const unsigned short* gA0 = Asw + (((long long)((m0 >> 4) + 2 * w) * kt) << 9) + l * 8;
    const unsigned short* gA1 = gA0 + ((long long)kt << 9);
    const unsigned short* gB0 = Bsw + (((long long)((n0 >> 4) + 2 * w) * kt) << 9) + l * 8;
    const unsigned short* gB1 = gB0 + ((long long)kt << 9);

    v4f acc[4][4];
#pragma unroll
    for (int i = 0; i < 4; i++)
#pragma unroll
        for (int j = 0; j < 4; j++) acc[i][j] = (v4f){0.f, 0.f, 0.f, 0.f};

#define STAGE(c) do {                                                       \
    const int b_ = (c) & 3;                                                 \
    const long long o_ = (long long)(c) << 9;                               \
    GLDS16(gA0 + o_, &As[b_][2 * w + 0][0]);                                \
    GLDS16(gA1 + o_, &As[b_][2 * w + 1][0]);                                \
    GLDS16(gB0 + o_, &Bs[b_][2 * w + 0][0]);                                \
    GLDS16(gB1 + o_, &Bs[b_][2 * w + 1][0]);                                \
} while (0)

#define COMPUTE(c) do {                                                     \
    const int b_ = (c) & 3;                                                 \
    v8bf af_[4], bf_[4];                                                    \
    _Pragma("unroll")                                                       \
    for (int i_ = 0; i_ < 4; i_++)                                          \
        af_[i_] = *(const v8bf*)(&As[b_][4 * wm + i_][l * 8]);              \
    _Pragma("unroll")                                                       \
    for (int j_ = 0; j_ < 4; j_++)                                          \
        bf_[j_] = *(const v8bf*)(&Bs[b_][4 * wn + j_][l * 8]);              \
    _Pragma("unroll")                                                       \
    for (int i_ = 0; i_ < 4; i_++)                                          \
    _Pragma("unroll")                                                       \
    for (int j_ = 0; j_ < 4; j_++)                                          \
        acc[i_][j_] = __builtin_amdgcn_mfma_f32_16x16x32_bf16(              \
            af_[i_], bf_[j_], acc[i_][j_], 0, 0, 0);                        \
} while (0)

    // prologue: chunks 0,1,2 -> bufs 0,1,2 (12 loads outstanding per wave)
    STAGE(0); STAGE(1); STAGE(2);

    // main: stage c+3 (16 out), wait to 12 (retires chunk c's 4, FIFO),
    // barrier (chunk c fully in LDS), compute, barrier (WAR for buf reuse).
    int c = 0;
    for (; c < kt - 3; ++c) {
        STAGE(c + 3);
        WAITC(12);
        BARRIER();
        COMPUTE(c);
        BARRIER();
    }
    // tail: drain 12 -> 8 -> 4 -> 0
    WAITC(8);  BARRIER(); COMPUTE(kt - 3); BARRIER();
    WAITC(4);  BARRIER(); COMPUTE(kt - 2); BARRIER();
    WAITC(0);  BARRIER(); COMPUTE(kt - 1);

#undef STAGE
#undef COMPUTE

    float bv[4];
#pragma unroll
    for (int j = 0; j < 4; j++) bv[j] = bias[n0 + 64 * wn + 16 * j + r16];
    const int colbase = n0 + 64 * wn + r16;
    const int nt = N >> 5;
#pragma unroll
    for (int i = 0; i < 4; i++) {
        int rowb = m0 + 64 * wm + 16 * i + qb * 4;
#pragma unroll
        for (int j = 0; j < 4; j++) {
            int col = colbase + 16 * j;
            float v[4];
#pragma unroll
            for (int r = 0; r < 4; r++) v[r] = acc[i][j][r] + bv[j];
            if (Ct && col >= ctcol0) {
                ushort4 o;
                o.x = f2bfu(v[0]); o.y = f2bfu(v[1]);
                o.z = f2bfu(v[2]); o.w = f2bfu(v[3]);
                *(ushort4*)(Ct + ((long long)(rowb >> 10) << 20)
                            + (long long)(col - ctcol0) * 1024 + (rowb & 1023)) = o;
            } else if (Csw) {
#pragma unroll
                for (int r = 0; r < 4; r++) {
                    int row = rowb + r;
                    float vv = v[r];
                    if (relu) vv = fmaxf(vv, 0.f);
                    Csw[swidx(row, col, nt)] = f2bfu(vv);
                }
            } else {
#pragma unroll
                for (int r = 0; r < 4; r++) {
                    int row = rowb + r;
                    long long off = (long long)row * ldC + col;
                    float vv = v[r];
                    if (res)  vv += res[off];
                    if (relu) vv = fmaxf(vv, 0.f);
                    if (Cf) Cf[off] = vv;
                    if (Cb) ((unsigned short*)Cb)[off] = f2bfu(vv);
                }
            }
        }
    }
}

// ---------------------------------------------------------------------------
// LDS-staged GEMM (R5) — kept for the conv frontend (row-remapped A).
// ---------------------------------------------------------------------------
__global__ __launch_bounds__(256) void gemm_mfma_k(
    const __hip_bfloat16* __restrict__ A, int rpbA, long long bstrideA, int ldA,
    const __hip_bfloat16* __restrict__ B,
    const float* __restrict__ bias,
    const float* __restrict__ res,
    float* __restrict__ Cf,
    __hip_bfloat16* __restrict__ Cb,
    int M, int N, int K, int ldC, int relu)
{
    __shared__ __align__(16) __hip_bfloat16 As[2][8][64][8];
    __shared__ __align__(16) __hip_bfloat16 Bs[2][4][64][8];
    const int t  = threadIdx.x;
    const int w  = t >> 6;
    const int l  = t & 63;
    const int m0 = blockIdx.y * 128;
    const int n0 = blockIdx.x * 64;
    const int r16 = l & 15;
    const int qb  = l >> 4;
    const int wm = w >> 1, wn = w & 1;

    const __hip_bfloat16* gA[2];
#pragma unroll
    for (int tt = 0; tt < 2; tt++) {
        int arow = m0 + 16 * (2 * w + tt) + r16;
        gA[tt] = A + (long long)(arow / rpbA) * bstrideA
                   + (long long)(arow % rpbA) * ldA + qb * 8;
    }
    const __hip_bfloat16* gB = B + (long long)(n0 + 16 * w + r16) * K + qb * 8;

    v4f acc[4][2];
#pragma unroll
    for (int i = 0; i < 4; i++)
#pragma unroll
        for (int j = 0; j < 2; j++) acc[i][j] = (v4f){0.f, 0.f, 0.f, 0.f};

    GLDS16(gA[0], &As[0][2 * w + 0][0][0]);
    GLDS16(gA[1], &As[0][2 * w + 1][0][0]);
    GLDS16(gB,    &Bs[0][w][0][0]);
    __syncthreads();

    int cur = 0;
    for (int k0 = 32; k0 < K; k0 += 32) {
        v8bf af[4], bfr[2];
#pragma unroll
        for (int i = 0; i < 4; i++) af[i]  = *(const v8bf*)(&As[cur][4 * wm + i][l][0]);
#pragma unroll
        for (int j = 0; j < 2; j++) bfr[j] = *(const v8bf*)(&Bs[cur][2 * wn + j][l][0]);
        GLDS16(gA[0] + k0, &As[cur ^ 1][2 * w + 0][0][0]);
        GLDS16(gA[1] + k0, &As[cur ^ 1][2 * w + 1][0][0]);
        GLDS16(gB + k0,    &Bs[cur ^ 1][w][0][0]);
#pragma unroll
        for (int i = 0; i < 4; i++)
#pragma unroll
            for (int j = 0; j < 2; j++)
                acc[i][j] = __builtin_amdgcn_mfma_f32_16x16x32_bf16(
                    af[i], bfr[j], acc[i][j], 0, 0, 0);
        __syncthreads();
        cur ^= 1;
    }
    {
        v8bf af[4], bfr[2];
#pragma unroll
        for (int i = 0; i < 4; i++) af[i]  = *(const v8bf*)(&As[cur][4 * wm + i][l][0]);
#pragma unroll
        for (int j = 0; j < 2; j++) bfr[j] = *(const v8bf*)(&Bs[cur][2 * wn + j][l][0]);
#pragma unroll
        for (int i = 0; i < 4; i++)
#pragma unroll
            for (int j = 0; j < 2; j++)
                acc[i][j] = __builtin_amdgcn_mfma_f32_16x16x32_bf16(
                    af[i], bfr[j], acc[i][j], 0, 0, 0);
    }

    float bv[2];
#pragma unroll
    for (int j = 0; j < 2; j++) bv[j] = bias[n0 + 32 * wn + 16 * j + r16];
    const int colbase = n0 + 32 * wn + r16;
#pragma unroll
    for (int i = 0; i < 4; i++) {
        int rowb = m0 + 64 * wm + 16 * i + qb * 4;
#pragma unroll
        for (int j = 0; j < 2; j++) {
            int col = colbase + 16 * j;
#pragma unroll
            for (int r = 0; r < 4; r++) {
                int row = rowb + r;
                if (row >= M) continue;
                long long off = (long long)row * ldC + col;
                float vv = acc[i][j][r] + bv[j];
                if (res)  vv += res[off];
                if (relu) vv = fmaxf(vv, 0.f);
                if (Cf) Cf[off] = vv;
                if (Cb) ((unsigned short*)Cb)[off] = f2bfu(vv);
            }
        }
    }
}

// ---------------------------------------------------------------------------
// MFMA softsign attention. Output written in SWIZZLED layout (K=1024 -> 32).
// ---------------------------------------------------------------------------
__global__ __launch_bounds__(256) void attn_mfma_k(
    const unsigned short* __restrict__ QKV,
    const unsigned short* __restrict__ Vt,
    unsigned short* __restrict__ Osw)
{
    __shared__ __align__(16) unsigned short lds[25600];
    const int t = threadIdx.x, w = t >> 6, l = t & 63;
    const int bh = blockIdx.y, b = bh >> 4, h = bh & 15;
    const int s0 = blockIdx.x << 7;
    const int r16 = l & 15, q4 = l >> 4;
    const long long qrow0 = (long long)(b << 10) + s0;
    const int hoff = h << 6;

#pragma unroll
    for (int mi = 0; mi < 2; mi++)
#pragma unroll
        for (int kk = 0; kk < 2; kk++) {
            const unsigned short* g = QKV + (qrow0 + 32 * w + 16 * mi + r16) * 3072
                                      + hoff + 32 * kk + q4 * 8;
            GLDS16(g, &lds[(w * 4 + mi * 2 + kk) * 512]);
        }
    __syncthreads();
    v8bf qf[2][2];
#pragma unroll
    for (int mi = 0; mi < 2; mi++)
#pragma unroll
        for (int kk = 0; kk < 2; kk++)
            qf[mi][kk] = *(const v8bf*)&lds[(w * 4 + mi * 2 + kk) * 512 + l * 8];

    v4f oacc[2][4];
#pragma unroll
    for (int i = 0; i < 2; i++)
#pragma unroll
        for (int j = 0; j < 4; j++) oacc[i][j] = (v4f){0.f, 0.f, 0.f, 0.f};

    for (int t0 = 0; t0 < 1024; t0 += 64) {
#pragma unroll
        for (int rr = 0; rr < 2; rr++) {
            int r = 2 * w + rr, kk = r >> 2, j = r & 3;
            const unsigned short* gk = QKV
                + ((long long)(b << 10) + t0 + 16 * j + r16) * 3072
                + 1024 + hoff + 32 * kk + q4 * 8;
            GLDS16(gk, &lds[8192 + r * 512]);
            const unsigned short* gv = Vt + ((long long)b << 20)
                + (long long)(hoff + 16 * j + r16) * 1024 + t0 + 32 * kk + q4 * 8;
            GLDS16(gv, &lds[12288 + r * 512]);
        }
        __syncthreads();

        v8bf kf[2][4];
#pragma unroll
        for (int kk = 0; kk < 2; kk++)
#pragma unroll
            for (int j = 0; j < 4; j++)
                kf[kk][j] = *(const v8bf*)&lds[8192 + (kk * 4 + j) * 512 + l * 8];
        v4f sc[2][4];
#pragma unroll
        for (int i = 0; i < 2; i++)
#pragma unroll
            for (int j = 0; j < 4; j++) sc[i][j] = (v4f){0.f, 0.f, 0.f, 0.f};
#pragma unroll
        for (int kk = 0; kk < 2; kk++)
#pragma unroll
            for (int mi = 0; mi < 2; mi++)
#pragma unroll
                for (int j = 0; j < 4; j++)
                    sc[mi][j] = __builtin_amdgcn_mfma_f32_16x16x32_bf16(
                        qf[mi][kk], kf[kk][j], sc[mi][j], 0, 0, 0);

#pragma unroll
        for (int mi = 0; mi < 2; mi++)
#pragma unroll
            for (int j = 0; j < 4; j++)
#pragma unroll
                for (int r = 0; r < 4; r++) {
                    float v = sc[mi][j][r] * 0.125f;
                    float p = v * __builtin_amdgcn_rcpf(1.0f + fabsf(v));
                    lds[16384 + (32 * w + 16 * mi + q4 * 4 + r) * 72 + 16 * j + r16] = f2bfu(p);
                }

        v8bf pf[2][2], vf[2][4];
#pragma unroll
        for (int mi = 0; mi < 2; mi++)
#pragma unroll
            for (int kk = 0; kk < 2; kk++)
                pf[mi][kk] = *(const v8bf*)&lds[16384 + (32 * w + 16 * mi + r16) * 72
                                                + 32 * kk + q4 * 8];
#pragma unroll
        for (int kk = 0; kk < 2; kk++)
#pragma unroll
            for (int j = 0; j < 4; j++)
                vf[kk][j] = *(const v8bf*)&lds[12288 + (kk * 4 + j) * 512 + l * 8];
#pragma unroll
        for (int kk = 0; kk < 2; kk++)
#pragma unroll
            for (int mi = 0; mi < 2; mi++)
#pragma unroll
                for (int j = 0; j < 4; j++)
                    oacc[mi][j] = __builtin_amdgcn_mfma_f32_16x16x32_bf16(
                        pf[mi][kk], vf[kk][j], oacc[mi][j], 0, 0, 0);
        __syncthreads();
    }

#pragma unroll
    for (int mi = 0; mi < 2; mi++)
#pragma unroll
        for (int j = 0; j < 4; j++)
#pragma unroll
            for (int r = 0; r < 4; r++)
                lds[(32 * w + 16 * mi + q4 * 4 + r) * 72 + 16 * j + r16] =
                    f2bfu(oacc[mi][j][r]);
    __syncthreads();
    {
        int row = t >> 1, ch = (t & 1) << 5;
        int grow = (int)qrow0 + row;
#pragma unroll
        for (int i = 0; i < 4; i++) {
            int c0 = hoff + ch + 8 * i;
            v8us vv = *(const v8us*)&lds[row * 72 + ch + 8 * i];
            *(v8us*)(Osw + swidx(grow, c0, 32)) = vv;
        }
    }
}

// ---------------------------------------------------------------------------
// LayerNorm (torch-style), output bf16 in SWIZZLED layout (K=1024).
// ---------------------------------------------------------------------------
__global__ __launch_bounds__(256) void layernorm_k(
    const float* __restrict__ x, const float* __restrict__ w,
    const float* __restrict__ b, unsigned short* __restrict__ ysw)
{
    int row = blockIdx.x;
    int t = threadIdx.x;
    float4 v = ((const float4*)(x + ((long long)row << 10)))[t];
    float s = v.x + v.y + v.z + v.w;
#pragma unroll
    for (int o = 32; o; o >>= 1) s += __shfl_down(s, o);
    __shared__ float red[4];
    __shared__ float red2[4];
    int wid = t >> 6, lane = t & 63;
    if (lane == 0) red[wid] = s;
    __syncthreads();
    float mean = (red[0] + red[1] + red[2] + red[3]) * (1.0f / 1024.0f);
    float dx = v.x - mean, dy = v.y - mean, dz = v.z - mean, dw = v.w - mean;
    float sq = dx * dx + dy * dy + dz * dz + dw * dw;
#pragma unroll
    for (int o = 32; o; o >>= 1) sq += __shfl_down(sq, o);
    if (lane == 0) red2[wid] = sq;
    __syncthreads();
    float var = (red2[0] + red2[1] + red2[2] + red2[3]) * (1.0f / 1023.0f);
    float inv = 1.0f / (sqrtf(var) + 1e-6f);
    float4 W  = ((const float4*)w)[t];
    float4 Bv = ((const float4*)b)[t];
    ushort4 o;
    o.x = f2bfu(W.x * (dx * inv) + Bv.x);
    o.y = f2bfu(W.y * (dy * inv) + Bv.y);
    o.z = f2bfu(W.z * (dz * inv) + Bv.z);
    o.w = f2bfu(W.w * (dw * inv) + Bv.w);
    int c0 = t << 2;
    *(ushort4*)(ysw + swidx(row, c0, 32)) = o;
}

// ---------------------------------------------------------------------------
__global__ __launch_bounds__(256) void add_pos_k(float* __restrict__ h)
{
    int idx = blockIdx.x * 256 + threadIdx.x;
    int d = idx & 1023;
    int s = (idx >> 10) & 1023;
    int e = d & ~1;
    float div = expf(-9.210340371976184f * (float)e * (1.0f / 1024.0f));
    float arg = (float)s * div;
    float pe = (d & 1) ? cosf(arg) : sinf(arg);
    h[idx] += pe;
}

__global__ __launch_bounds__(256) void convert_k(
    const float* __restrict__ src, unsigned short* __restrict__ dst, int n4)
{
    int i = blockIdx.x * 256 + threadIdx.x;
    if (i >= n4) return;
    float4 v = ((const float4*)src)[i];
    ushort4 o;
    o.x = f2bfu(v.x); o.y = f2bfu(v.y); o.z = f2bfu(v.z); o.w = f2bfu(v.w);
    ((ushort4*)dst)[i] = o;
}

// Layer weights fp32 row-major -> bf16 SWIZZLED, all 6 matrices, one launch.
// dst layout (us): q,k,v,o (1M each), f1 (2M), f2 (2M) — contiguous.
__global__ __launch_bounds__(256) void convert_layer_sw_k(
    const float* __restrict__ q, const float* __restrict__ k,
    const float* __restrict__ v, const float* __restrict__ o,
    const float* __restrict__ f1, const float* __restrict__ f2,
    unsigned short* __restrict__ dst)
{
    int idx = blockIdx.x * 256 + threadIdx.x;   // float4 index, [0, 2M)
    const float* src;
    unsigned short* db;
    int Ksh, rf;
    if (idx < 0x100000) {
        int region = idx >> 18;
        rf = idx & 0x3FFFF;
        src = (region == 0) ? q : (region == 1) ? k : (region == 2) ? v : o;
        db = dst + ((long long)region << 20);
        Ksh = 10;
    } else if (idx < 0x180000) {
        rf = idx - 0x100000; src = f1; db = dst + (4LL << 20); Ksh = 10;
    } else {
        rf = idx - 0x180000; src = f2; db = dst + (6LL << 20); Ksh = 11;
    }
    float4 vv = ((const float4*)src)[rf];
    int flatf = rf << 2;
    int n  = flatf >> Ksh;
    int k0 = flatf & ((1 << Ksh) - 1);
    ushort4 ov;
    ov.x = f2bfu(vv.x); ov.y = f2bfu(vv.y); ov.z = f2bfu(vv.z); ov.w = f2bfu(vv.w);
    *(ushort4*)(db + swidx(n, k0, 1 << (Ksh - 5))) = ov;
}

__global__ __launch_bounds__(256) void concat3_k(
    const float* __restrict__ a, const float* __restrict__ b,
    const float* __restrict__ c, float* __restrict__ o)
{
    int i = blockIdx.x * 256 + threadIdx.x;
    o[i] = (i < 1024) ? a[i] : ((i < 2048) ? b[i - 1024] : c[i - 2048]);
}

__global__ __launch_bounds__(256) void reorder_w_k(
    const float* __restrict__ src, unsigned short* __restrict__ dst, int OC, int IC)
{
    int idx = blockIdx.x * 256 + threadIdx.x;
    if (idx >= OC * IC * 3) return;
    int k  = idx % 3;
    int ic = (idx / 3) % IC;
    int oc = idx / (3 * IC);
    dst[(oc * 3 + k) * IC + ic] = f2bfu(src[idx]);
}

// meanpool split: 256-block partial pass (16 rows each, all 1024 d) then a
// 16-block reduce. Old single-pass version ran on only 16 CUs pulling 16 MB.
__global__ __launch_bounds__(256) void meanpool_part_k(
    const float* __restrict__ h, float* __restrict__ part)
{
    int g = blockIdx.x;                 // g = b*64 + rblk
    int b = g >> 6, rblk = g & 63;
    const float4* base = (const float4*)(h + ((long long)b << 20)
                                           + ((long long)(rblk * 16) << 10));
    float4 s = {0.f, 0.f, 0.f, 0.f};
#pragma unroll
    for (int i = 0; i < 16; i++) {
        float4 v = base[i * 256 + threadIdx.x];
        s.x += v.x; s.y += v.y; s.z += v.z; s.w += v.w;
    }
    ((float4*)part)[g * 256 + threadIdx.x] = s;
}

__global__ __launch_bounds__(256) void meanpool_red_k(
    const float* __restrict__ part, float* __restrict__ pooled)
{
    int idx = blockIdx.x * 256 + threadIdx.x;   // 4096: b = idx>>10, d = idx&1023
    int b = idx >> 10, d = idx & 1023;
    const float* p = part + ((long long)(b * 64) << 10) + d;
    float s = 0.f;
#pragma unroll 8
    for (int r = 0; r < 64; r++) s += p[r << 10];
    pooled[idx] = s * (1.0f / 1024.0f);
}

__global__ __launch_bounds__(256) void fc_k(
    const float* __restrict__ p, const float* __restrict__ w,
    const float* __restrict__ fb, float* __restrict__ out)
{
    int b = blockIdx.x, t = threadIdx.x;
    float s = 0.f;
    for (int i = t; i < 1024; i += 256) s += p[(b << 10) + i] * w[i];
#pragma unroll
    for (int o = 32; o; o >>= 1) s += __shfl_down(s, o);
    __shared__ float red[4];
    if ((t & 63) == 0) red[t >> 6] = s;
    __syncthreads();
    if (t == 0) out[b] = red[0] + red[1] + red[2] + red[3] + fb[0];
}

// ---------------------------------------------------------------------------
extern "C" void kernel_launch(void* const* d_in, const int* in_sizes, int n_in,
                              void* d_out, int out_size, void* d_ws, size_t ws_size,
                              hipStream_t stream)
{
    const float* x    = (const float*)d_in[0];
    const float* c1w  = (const float*)d_in[1];
    const float* c1b  = (const float*)d_in[2];
    const float* c2w  = (const float*)d_in[3];
    const float* c2b  = (const float*)d_in[4];
    const float* lnAw = (const float*)d_in[5];
    const float* lnAb = (const float*)d_in[6];
    const float* qw   = (const float*)d_in[7];
    const float* qbi  = (const float*)d_in[8];
    const float* kw   = (const float*)d_in[9];
    const float* kbi  = (const float*)d_in[10];
    const float* vw   = (const float*)d_in[11];
    const float* vbi  = (const float*)d_in[12];
    const float* ow   = (const float*)d_in[13];
    const float* obi  = (const float*)d_in[14];
    const float* lnBw = (const float*)d_in[15];
    const float* lnBb = (const float*)d_in[16];
    const float* f1w  = (const float*)d_in[17];
    const float* f1b  = (const float*)d_in[18];
    const float* f2w  = (const float*)d_in[19];
    const float* f2b  = (const float*)d_in[20];
    const float* fcw  = (const float*)d_in[21];
    const float* fcb  = (const float*)d_in[22];
    float* out = (float*)d_out;

    float* ws = (float*)d_ws;
    typedef __hip_bfloat16 bf;
    typedef unsigned short us;
    float* h    = ws;                          // 4,194,304 f
    us* hn_b    = (us*)(ws + 4194304);         // 4M us (swizzled activations)
    us* qkv_b   = (us*)(ws + 6291456);         // [4096][3072] us row-major
    us* ff_b    = qkv_b;                       // [4096][2048] swizzled overlay
    us* wq_b    = (us*)(ws + 12582912);        // swizzled: q,k,v,o,f1,f2
    us* wo_b    = (us*)(ws + 14155776);
    us* wf1_b   = (us*)(ws + 14680064);
    us* wf2_b   = (us*)(ws + 15728640);
    us* xb      = (us*)(ws + 16777216);
    us* h1b     = (us*)(ws + 16912896);
    us* w1t_b   = (us*)(ws + 17963520);
    us* w2t_b   = (us*)(ws + 18012672);
    float* pooled = ws + 18799104;             // 4,096 f
    us* Vt      = (us*)(ws + 18803200);        // [4][1024 d][1024 t] us
    float* bqkv = ws + 20900352;               // 3,072 f
    float* mp_part = ws + 20903424;            // 262,144 f (meanpool partials)

    convert_k<<<dim3(257), 256, 0, stream>>>(x, xb, 65792);
    reorder_w_k<<<dim3(384),  256, 0, stream>>>(c1w, w1t_b, 512, 64);
    reorder_w_k<<<dim3(6144), 256, 0, stream>>>(c2w, w2t_b, 1024, 512);

    // conv1: M=4104, N=512, K=192 (LDS-staged kernel, row-remapped A)
    gemm_mfma_k<<<dim3(8, 33), 256, 0, stream>>>(
        (const bf*)xb, 1026, 1028LL * 64, 64, (const bf*)w1t_b,
        c1b, nullptr, nullptr, (bf*)h1b, 4104, 512, 192, 512, 0);
    // conv2: M=4096, N=1024, K=1536
    gemm_mfma_k<<<dim3(16, 32), 256, 0, stream>>>(
        (const bf*)h1b, 1024, 1026LL * 512, 512, (const bf*)w2t_b,
        c2b, nullptr, h, nullptr, 4096, 1024, 1536, 1024, 0);
    add_pos_k<<<dim3(16384), 256, 0, stream>>>(h);

    for (int l = 0; l < 4; l++) {
        long long wo  = (long long)l * 1048576;
        long long wo2 = (long long)l * 2097152;
        convert_layer_sw_k<<<dim3(8192), 256, 0, stream>>>(
            qw + wo, kw + wo, vw + wo, ow + wo, f1w + wo2, f2w + wo2, wq_b);
        concat3_k<<<dim3(12), 256, 0, stream>>>(qbi + l * 1024, kbi + l * 1024,
                                                vbi + l * 1024, bqkv);

        layernorm_k<<<dim3(4096), 256, 0, stream>>>(h, lnAw + l * 1024, lnAb + l * 1024, hn_b);
        // fused QKV: N=3072; Q,K swizzled to qkv_b; V transposed to Vt
        gemm_sw_k<<<dim3(24, 32), 256, 0, stream>>>(
            hn_b, wq_b, bqkv, nullptr, nullptr, qkv_b, nullptr, Vt, 2048,
            4096, 3072, 1024, 3072, 0);
        attn_mfma_k<<<dim3(8, 64), 256, 0, stream>>>(qkv_b, Vt, hn_b);
        // O-proj: out fp32 h += res
        gemm_sw_k<<<dim3(8, 32), 256, 0, stream>>>(
            hn_b, wo_b, obi + l * 1024, h, h, nullptr, nullptr, nullptr, 0,
            4096, 1024, 1024, 1024, 0);
        layernorm_k<<<dim3(4096), 256, 0, stream>>>(h, lnBw + l * 1024, lnBb + l * 1024, hn_b);
        // FF1: out swizzled bf16 (+relu)
        gemm_sw_k<<<dim3(16, 32), 256, 0, stream>>>(
            hn_b, wf1_b, f1b + l * 2048, nullptr, nullptr, nullptr, ff_b, nullptr, 0,
            4096, 2048, 1024, 2048, 1);
        // FF2: out fp32 h += res
        gemm_sw_k<<<dim3(8, 32), 256, 0, stream>>>(
            ff_b, wf2_b, f2b + l * 1024, h, h, nullptr, nullptr, nullptr, 0,
            4096, 1024, 2048, 1024, 0);
    }

    meanpool_part_k<<<dim3(256), 256, 0, stream>>>(h, mp_part);
    meanpool_red_k<<<dim3(16), 256, 0, stream>>>(mp_part, pooled);
    fc_k<<<dim3(4), 256, 0, stream>>>(pooled, fcw, fcb, out);
}

// Round 9
// 1122.040 us; speedup vs baseline: 1.4648x; 1.1305x over previous
//
#include <hip/hip_runtime.h>
#include <hip/hip_bf16.h>
#include <math.h>

// ---------------------------------------------------------------------------
// helpers
// ---------------------------------------------------------------------------
typedef __bf16 v8bf __attribute__((ext_vector_type(8)));
typedef float  v4f  __attribute__((ext_vector_type(4)));
typedef unsigned short v8us __attribute__((ext_vector_type(8)));

__device__ __forceinline__ unsigned short f2bfu(float f) {
    unsigned u = __builtin_bit_cast(unsigned, f);
    unsigned r = (u + 0x7fffu + ((u >> 16) & 1u)) >> 16;
    return (unsigned short)r;
}
__device__ __forceinline__ float bf2f(unsigned short u) {
    unsigned x = ((unsigned)u) << 16;
    return __builtin_bit_cast(float, x);
}

// fragment-swizzled element address: matrix [rows][K cols] stored so that a
// wave's 16x32 MFMA fragment is contiguous: sw(r,k) =
//   tile(r>>4, k>>5) * 512 + lane((k>>3)&3, r&15) * 8 + (k&7)
__device__ __forceinline__ long long swidx(int r, int k, int kt /*=K>>5*/) {
    return ((long long)((r >> 4) * kt + (k >> 5)) << 9)
         + (((k >> 3) & 3) << 7) + ((r & 15) << 3) + (k & 7);
}

#define GLDS16(g, s)                                                        \
    __builtin_amdgcn_global_load_lds(                                       \
        (const __attribute__((address_space(1))) void*)(g),                 \
        (__attribute__((address_space(3))) void*)(s), 16, 0, 0)

// ---------------------------------------------------------------------------
// SWIZZLED register-direct bf16 MFMA GEMM (no LDS, no barriers).
// A (M x K) and B (N x K) in fragment-swizzled layout (see swidx).
// ONE WAVE PER BLOCK (64 threads), wave tile 64x64, R4's branch-free
// depth-4 ring body (collapsed by the compiler to ~1 chunk in flight,
// which is FINE — see below).
//
// R1-R8 synthesis: every register-direct variant is pinned at
//   time ≈ (FETCH_SIZE + WRITE_SIZE) / ~2.0 TB/s
// (R1 106MB/53µs, R4 97/50, R5 125/62.7, R6 121/62 — all on the same
// line). The GEMM is L2-MISS-PATH BOUND, not schedule-bound: the old
// bx-fast ordering gives each XCD a ~7MB working set vs its 4MB L2 ->
// FETCH runs ~5x compulsory. MfmaUtil ~18% is the ceiling's duty cycle,
// which is why six schedule rewrites never moved it.
//
// This round changes ONLY the block-index mapping: the (by,bx) grid is
// partitioned into 8 L2-sized regions (4 by-strips x 2 bx-strips), one
// per XCD via bid&7 (same XCD-selector assumption as the m192-verified
// swizzle). Within a region, blocks are ordered in 4x4 micro-tiles,
// micro-rows major: the B-region (<=3MB) stays L2-resident across row
// sweeps while A streams -> per-XCD fetch approaches compulsory
// (QKV: 5MB/XCD -> ~40MB total vs 72 measured).
// Guard: nbx%8==0 && nby%16==0 (all gemm grids here qualify).
//
// Outputs: Cf (fp32,+res row-major) | Cb (bf16 row-major) | Csw (bf16
// swizzled for the next GEMM, K_consumer = N) ; cols >= ctcol0 (Ct!=null)
// go transposed to Ct (attention V^T). M,N multiples of 64, kt=K/32
// a multiple of 4 and >= 8 (kt = 32 or 64 here).
// ---------------------------------------------------------------------------
#define LOAD_CHUNK(R, C) do {                                               \
    const long long o_ = (long long)(C) << 9;                               \
    _Pragma("unroll")                                                       \
    for (int i_ = 0; i_ < 4; i_++) Ab[R][i_] = *(const v8bf*)(pa[i_] + o_); \
    _Pragma("unroll")                                                       \
    for (int j_ = 0; j_ < 4; j_++) Bb[R][j_] = *(const v8bf*)(pb[j_] + o_); \
} while (0)

#define MFMA_CHUNK(R) do {                                                  \
    _Pragma("unroll")                                                       \
    for (int i_ = 0; i_ < 4; i_++)                                          \
    _Pragma("unroll")                                                       \
    for (int j_ = 0; j_ < 4; j_++)                                          \
        acc[i_][j_] = __builtin_amdgcn_mfma_f32_16x16x32_bf16(              \
            Ab[R][i_], Bb[R][j_], acc[i_][j_], 0, 0, 0);                    \
} while (0)

__global__ __launch_bounds__(64, 2) void gemm_sw_k(
    const unsigned short* __restrict__ Asw,
    const unsigned short* __restrict__ Bsw,
    const float* __restrict__ bias,
    const float* __restrict__ res,
    float* __restrict__ Cf,
    unsigned short* __restrict__ Cb,
    unsigned short* __restrict__ Csw,
    unsigned short* __restrict__ Ct, int ctcol0,
    int M, int N, int K, int ldC, int relu)
{
    const int l = threadIdx.x;

    int bx = blockIdx.x, by = blockIdx.y;
    {
        int nbx = gridDim.x, nby = gridDim.y;
        if (((nbx & 7) == 0) && ((nby & 15) == 0)) {
            // L2-locality mapping: 8 XCD regions (4 by-strips x 2 bx-strips),
            // 4x4 micro-tiles inside, micro-rows major. Bijective.
            int bid   = by * nbx + bx;
            int xcd   = bid & 7;
            int local = bid >> 3;             // [0, nb/8)
            int rby = nby >> 2;               // region height (blocks)
            int rbx = nbx >> 1;               // region width
            int u   = local & 15;             // 4x4 micro-tile cell
            int mt  = local >> 4;             // micro-tile index
            int mtxc = rbx >> 2;              // micro-tiles per region row
            int mty = mt / mtxc;
            int mtx = mt - mty * mtxc;
            by = (xcd >> 1) * rby + (mty << 2) + (u >> 2);
            bx = (xcd & 1) * rbx + (mtx << 2) + (u & 3);
        } else {
            int nb = nbx * nby;
            if ((nb & 7) == 0) {              // fallback: old XCD swizzle
                int bid = by * nbx + bx;
                int nid = (bid & 7) * (nb >> 3) + (bid >> 3);
                by = nid / nbx;
                bx = nid - by * nbx;
            }
        }
    }
    const int m0 = by * 64;
    const int n0 = bx * 64;
    const int r16 = l & 15;
    const int qb  = l >> 4;
    const int kt = K >> 5;

    // fragment base pointers: contiguous 16B per lane
    const unsigned short* pa[4];
#pragma unroll
    for (int i = 0; i < 4; i++)
        pa[i] = Asw + ((long long)(((m0 >> 4) + i) * kt) << 9) + l * 8;
    const unsigned short* pb[4];
#pragma unroll
    for (int j = 0; j < 4; j++)
        pb[j] = Bsw + ((long long)(((n0 >> 4) + j) * kt) << 9) + l * 8;

    v4f acc[4][4];
#pragma unroll
    for (int i = 0; i < 4; i++)
#pragma unroll
        for (int j = 0; j < 4; j++) acc[i][j] = (v4f){0.f, 0.f, 0.f, 0.f};

    v8bf Ab[4][4], Bb[4][4];

    // prologue: chunks 0,1,2 -> rings 0,1,2
    LOAD_CHUNK(0, 0);
    LOAD_CHUNK(1, 1);
    LOAD_CHUNK(2, 2);

    // steady state: straight-line, no branches, literal ring indices.
    int s = 0;
    for (; s < kt - 4; s += 4) {
        LOAD_CHUNK(3, s + 3); MFMA_CHUNK(0);
        LOAD_CHUNK(0, s + 4); MFMA_CHUNK(1);
        LOAD_CHUNK(1, s + 5); MFMA_CHUNK(2);
        LOAD_CHUNK(2, s + 6); MFMA_CHUNK(3);
    }
    // epilogue: s == kt-4; rings hold kt-4,kt-3,kt-2; load last chunk.
    LOAD_CHUNK(3, kt - 1);
    MFMA_CHUNK(0); MFMA_CHUNK(1); MFMA_CHUNK(2); MFMA_CHUNK(3);

    float bv[4];
#pragma unroll
    for (int j = 0; j < 4; j++) bv[j] = bias[n0 + 16 * j + r16];
    const int colbase = n0 + r16;
    const int nt = N >> 5;
#pragma unroll
    for (int i = 0; i < 4; i++) {
        int rowb = m0 + 16 * i + qb * 4;
#pragma unroll
        for (int j = 0; j < 4; j++) {
            int col = colbase + 16 * j;
            float v[4];
#pragma unroll
            for (int r = 0; r < 4; r++) v[r] = acc[i][j][r] + bv[j];
            if (Ct && col >= ctcol0) {
                ushort4 o;
                o.x = f2bfu(v[0]); o.y = f2bfu(v[1]);
                o.z = f2bfu(v[2]); o.w = f2bfu(v[3]);
                *(ushort4*)(Ct + ((long long)(rowb >> 10) << 20)
                            + (long long)(col - ctcol0) * 1024 + (rowb & 1023)) = o;
            } else if (Csw) {
#pragma unroll
                for (int r = 0; r < 4; r++) {
                    int row = rowb + r;
                    float vv = v[r];
                    if (relu) vv = fmaxf(vv, 0.f);
                    Csw[swidx(row, col, nt)] = f2bfu(vv);
                }
            } else {
#pragma unroll
                for (int r = 0; r < 4; r++) {
                    int row = rowb + r;
                    long long off = (long long)row * ldC + col;
                    float vv = v[r];
                    if (res)  vv += res[off];
                    if (relu) vv = fmaxf(vv, 0.f);
                    if (Cf) Cf[off] = vv;
                    if (Cb) ((unsigned short*)Cb)[off] = f2bfu(vv);
                }
            }
        }
    }
}

// ---------------------------------------------------------------------------
// LDS-staged GEMM (R5) — kept for the conv frontend (row-remapped A).
// ---------------------------------------------------------------------------
__global__ __launch_bounds__(256) void gemm_mfma_k(
    const __hip_bfloat16* __restrict__ A, int rpbA, long long bstrideA, int ldA,
    const __hip_bfloat16* __restrict__ B,
    const float* __restrict__ bias,
    const float* __restrict__ res,
    float* __restrict__ Cf,
    __hip_bfloat16* __restrict__ Cb,
    int M, int N, int K, int ldC, int relu)
{
    __shared__ __align__(16) __hip_bfloat16 As[2][8][64][8];
    __shared__ __align__(16) __hip_bfloat16 Bs[2][4][64][8];
    const int t  = threadIdx.x;
    const int w  = t >> 6;
    const int l  = t & 63;
    const int m0 = blockIdx.y * 128;
    const int n0 = blockIdx.x * 64;
    const int r16 = l & 15;
    const int qb  = l >> 4;
    const int wm = w >> 1, wn = w & 1;

    const __hip_bfloat16* gA[2];
#pragma unroll
    for (int tt = 0; tt < 2; tt++) {
        int arow = m0 + 16 * (2 * w + tt) + r16;
        gA[tt] = A + (long long)(arow / rpbA) * bstrideA
                   + (long long)(arow % rpbA) * ldA + qb * 8;
    }
    const __hip_bfloat16* gB = B + (long long)(n0 + 16 * w + r16) * K + qb * 8;

    v4f acc[4][2];
#pragma unroll
    for (int i = 0; i < 4; i++)
#pragma unroll
        for (int j = 0; j < 2; j++) acc[i][j] = (v4f){0.f, 0.f, 0.f, 0.f};

    GLDS16(gA[0], &As[0][2 * w + 0][0][0]);
    GLDS16(gA[1], &As[0][2 * w + 1][0][0]);
    GLDS16(gB,    &Bs[0][w][0][0]);
    __syncthreads();

    int cur = 0;
    for (int k0 = 32; k0 < K; k0 += 32) {
        v8bf af[4], bfr[2];
#pragma unroll
        for (int i = 0; i < 4; i++) af[i]  = *(const v8bf*)(&As[cur][4 * wm + i][l][0]);
#pragma unroll
        for (int j = 0; j < 2; j++) bfr[j] = *(const v8bf*)(&Bs[cur][2 * wn + j][l][0]);
        GLDS16(gA[0] + k0, &As[cur ^ 1][2 * w + 0][0][0]);
        GLDS16(gA[1] + k0, &As[cur ^ 1][2 * w + 1][0][0]);
        GLDS16(gB + k0,    &Bs[cur ^ 1][w][0][0]);
#pragma unroll
        for (int i = 0; i < 4; i++)
#pragma unroll
            for (int j = 0; j < 2; j++)
                acc[i][j] = __builtin_amdgcn_mfma_f32_16x16x32_bf16(
                    af[i], bfr[j], acc[i][j], 0, 0, 0);
        __syncthreads();
        cur ^= 1;
    }
    {
        v8bf af[4], bfr[2];
#pragma unroll
        for (int i = 0; i < 4; i++) af[i]  = *(const v8bf*)(&As[cur][4 * wm + i][l][0]);
#pragma unroll
        for (int j = 0; j < 2; j++) bfr[j] = *(const v8bf*)(&Bs[cur][2 * wn + j][l][0]);
#pragma unroll
        for (int i = 0; i < 4; i++)
#pragma unroll
            for (int j = 0; j < 2; j++)
                acc[i][j] = __builtin_amdgcn_mfma_f32_16x16x32_bf16(
                    af[i], bfr[j], acc[i][j], 0, 0, 0);
    }

    float bv[2];
#pragma unroll
    for (int j = 0; j < 2; j++) bv[j] = bias[n0 + 32 * wn + 16 * j + r16];
    const int colbase = n0 + 32 * wn + r16;
#pragma unroll
    for (int i = 0; i < 4; i++) {
        int rowb = m0 + 64 * wm + 16 * i + qb * 4;
#pragma unroll
        for (int j = 0; j < 2; j++) {
            int col = colbase + 16 * j;
#pragma unroll
            for (int r = 0; r < 4; r++) {
                int row = rowb + r;
                if (row >= M) continue;
                long long off = (long long)row * ldC + col;
                float vv = acc[i][j][r] + bv[j];
                if (res)  vv += res[off];
                if (relu) vv = fmaxf(vv, 0.f);
                if (Cf) Cf[off] = vv;
                if (Cb) ((unsigned short*)Cb)[off] = f2bfu(vv);
            }
        }
    }
}

// ---------------------------------------------------------------------------
// MFMA softsign attention. Output written in SWIZZLED layout (K=1024 -> 32).
// ---------------------------------------------------------------------------
__global__ __launch_bounds__(256) void attn_mfma_k(
    const unsigned short* __restrict__ QKV,
    const unsigned short* __restrict__ Vt,
    unsigned short* __restrict__ Osw)
{
    __shared__ __align__(16) unsigned short lds[25600];
    const int t = threadIdx.x, w = t >> 6, l = t & 63;
    const int bh = blockIdx.y, b = bh >> 4, h = bh & 15;
    const int s0 = blockIdx.x << 7;
    const int r16 = l & 15, q4 = l >> 4;
    const long long qrow0 = (long long)(b << 10) + s0;
    const int hoff = h << 6;

#pragma unroll
    for (int mi = 0; mi < 2; mi++)
#pragma unroll
        for (int kk = 0; kk < 2; kk++) {
            const unsigned short* g = QKV + (qrow0 + 32 * w + 16 * mi + r16) * 3072
                                      + hoff + 32 * kk + q4 * 8;
            GLDS16(g, &lds[(w * 4 + mi * 2 + kk) * 512]);
        }
    __syncthreads();
    v8bf qf[2][2];
#pragma unroll
    for (int mi = 0; mi < 2; mi++)
#pragma unroll
        for (int kk = 0; kk < 2; kk++)
            qf[mi][kk] = *(const v8bf*)&lds[(w * 4 + mi * 2 + kk) * 512 + l * 8];

    v4f oacc[2][4];
#pragma unroll
    for (int i = 0; i < 2; i++)
#pragma unroll
        for (int j = 0; j < 4; j++) oacc[i][j] = (v4f){0.f, 0.f, 0.f, 0.f};

    for (int t0 = 0; t0 < 1024; t0 += 64) {
#pragma unroll
        for (int rr = 0; rr < 2; rr++) {
            int r = 2 * w + rr, kk = r >> 2, j = r & 3;
            const unsigned short* gk = QKV
                + ((long long)(b << 10) + t0 + 16 * j + r16) * 3072
                + 1024 + hoff + 32 * kk + q4 * 8;
            GLDS16(gk, &lds[8192 + r * 512]);
            const unsigned short* gv = Vt + ((long long)b << 20)
                + (long long)(hoff + 16 * j + r16) * 1024 + t0 + 32 * kk + q4 * 8;
            GLDS16(gv, &lds[12288 + r * 512]);
        }
        __syncthreads();

        v8bf kf[2][4];
#pragma unroll
        for (int kk = 0; kk < 2; kk++)
#pragma unroll
            for (int j = 0; j < 4; j++)
                kf[kk][j] = *(const v8bf*)&lds[8192 + (kk * 4 + j) * 512 + l * 8];
        v4f sc[2][4];
#pragma unroll
        for (int i = 0; i < 2; i++)
#pragma unroll
            for (int j = 0; j < 4; j++) sc[i][j] = (v4f){0.f, 0.f, 0.f, 0.f};
#pragma unroll
        for (int kk = 0; kk < 2; kk++)
#pragma unroll
            for (int mi = 0; mi < 2; mi++)
#pragma unroll
                for (int j = 0; j < 4; j++)
                    sc[mi][j] = __builtin_amdgcn_mfma_f32_16x16x32_bf16(
                        qf[mi][kk], kf[kk][j], sc[mi][j], 0, 0, 0);

#pragma unroll
        for (int mi = 0; mi < 2; mi++)
#pragma unroll
            for (int j = 0; j < 4; j++)
#pragma unroll
                for (int r = 0; r < 4; r++) {
                    float v = sc[mi][j][r] * 0.125f;
                    float p = v * __builtin_amdgcn_rcpf(1.0f + fabsf(v));
                    lds[16384 + (32 * w + 16 * mi + q4 * 4 + r) * 72 + 16 * j + r16] = f2bfu(p);
                }

        v8bf pf[2][2], vf[2][4];
#pragma unroll
        for (int mi = 0; mi < 2; mi++)
#pragma unroll
            for (int kk = 0; kk < 2; kk++)
                pf[mi][kk] = *(const v8bf*)&lds[16384 + (32 * w + 16 * mi + r16) * 72
                                                + 32 * kk + q4 * 8];
#pragma unroll
        for (int kk = 0; kk < 2; kk++)
#pragma unroll
            for (int j = 0; j < 4; j++)
                vf[kk][j] = *(const v8bf*)&lds[12288 + (kk * 4 + j) * 512 + l * 8];
#pragma unroll
        for (int kk = 0; kk < 2; kk++)
#pragma unroll
            for (int mi = 0; mi < 2; mi++)
#pragma unroll
                for (int j = 0; j < 4; j++)
                    oacc[mi][j] = __builtin_amdgcn_mfma_f32_16x16x32_bf16(
                        pf[mi][kk], vf[kk][j], oacc[mi][j], 0, 0, 0);
        __syncthreads();
    }

#pragma unroll
    for (int mi = 0; mi < 2; mi++)
#pragma unroll
        for (int j = 0; j < 4; j++)
#pragma unroll
            for (int r = 0; r < 4; r++)
                lds[(32 * w + 16 * mi + q4 * 4 + r) * 72 + 16 * j + r16] =
                    f2bfu(oacc[mi][j][r]);
    __syncthreads();
    {
        int row = t >> 1, ch = (t & 1) << 5;
        int grow = (int)qrow0 + row;
#pragma unroll
        for (int i = 0; i < 4; i++) {
            int c0 = hoff + ch + 8 * i;
            v8us vv = *(const v8us*)&lds[row * 72 + ch + 8 * i];
            *(v8us*)(Osw + swidx(grow, c0, 32)) = vv;
        }
    }
}

// ---------------------------------------------------------------------------
// LayerNorm (torch-style), output bf16 in SWIZZLED layout (K=1024).
// ---------------------------------------------------------------------------
__global__ __launch_bounds__(256) void layernorm_k(
    const float* __restrict__ x, const float* __restrict__ w,
    const float* __restrict__ b, unsigned short* __restrict__ ysw)
{
    int row = blockIdx.x;
    int t = threadIdx.x;
    float4 v = ((const float4*)(x + ((long long)row << 10)))[t];
    float s = v.x + v.y + v.z + v.w;
#pragma unroll
    for (int o = 32; o; o >>= 1) s += __shfl_down(s, o);
    __shared__ float red[4];
    __shared__ float red2[4];
    int wid = t >> 6, lane = t & 63;
    if (lane == 0) red[wid] = s;
    __syncthreads();
    float mean = (red[0] + red[1] + red[2] + red[3]) * (1.0f / 1024.0f);
    float dx = v.x - mean, dy = v.y - mean, dz = v.z - mean, dw = v.w - mean;
    float sq = dx * dx + dy * dy + dz * dz + dw * dw;
#pragma unroll
    for (int o = 32; o; o >>= 1) sq += __shfl_down(sq, o);
    if (lane == 0) red2[wid] = sq;
    __syncthreads();
    float var = (red2[0] + red2[1] + red2[2] + red2[3]) * (1.0f / 1023.0f);
    float inv = 1.0f / (sqrtf(var) + 1e-6f);
    float4 W  = ((const float4*)w)[t];
    float4 Bv = ((const float4*)b)[t];
    ushort4 o;
    o.x = f2bfu(W.x * (dx * inv) + Bv.x);
    o.y = f2bfu(W.y * (dy * inv) + Bv.y);
    o.z = f2bfu(W.z * (dz * inv) + Bv.z);
    o.w = f2bfu(W.w * (dw * inv) + Bv.w);
    int c0 = t << 2;
    *(ushort4*)(ysw + swidx(row, c0, 32)) = o;
}

// ---------------------------------------------------------------------------
__global__ __launch_bounds__(256) void add_pos_k(float* __restrict__ h)
{
    int idx = blockIdx.x * 256 + threadIdx.x;
    int d = idx & 1023;
    int s = (idx >> 10) & 1023;
    int e = d & ~1;
    float div = expf(-9.210340371976184f * (float)e * (1.0f / 1024.0f));
    float arg = (float)s * div;
    float pe = (d & 1) ? cosf(arg) : sinf(arg);
    h[idx] += pe;
}

__global__ __launch_bounds__(256) void convert_k(
    const float* __restrict__ src, unsigned short* __restrict__ dst, int n4)
{
    int i = blockIdx.x * 256 + threadIdx.x;
    if (i >= n4) return;
    float4 v = ((const float4*)src)[i];
    ushort4 o;
    o.x = f2bfu(v.x); o.y = f2bfu(v.y); o.z = f2bfu(v.z); o.w = f2bfu(v.w);
    ((ushort4*)dst)[i] = o;
}

// Layer weights fp32 row-major -> bf16 SWIZZLED, all 6 matrices, one launch.
// dst layout (us): q,k,v,o (1M each), f1 (2M), f2 (2M) — contiguous.
__global__ __launch_bounds__(256) void convert_layer_sw_k(
    const float* __restrict__ q, const float* __restrict__ k,
    const float* __restrict__ v, const float* __restrict__ o,
    const float* __restrict__ f1, const float* __restrict__ f2,
    unsigned short* __restrict__ dst)
{
    int idx = blockIdx.x * 256 + threadIdx.x;   // float4 index, [0, 2M)
    const float* src;
    unsigned short* db;
    int Ksh, rf;
    if (idx < 0x100000) {
        int region = idx >> 18;
        rf = idx & 0x3FFFF;
        src = (region == 0) ? q : (region == 1) ? k : (region == 2) ? v : o;
        db = dst + ((long long)region << 20);
        Ksh = 10;
    } else if (idx < 0x180000) {
        rf = idx - 0x100000; src = f1; db = dst + (4LL << 20); Ksh = 10;
    } else {
        rf = idx - 0x180000; src = f2; db = dst + (6LL << 20); Ksh = 11;
    }
    float4 vv = ((const float4*)src)[rf];
    int flatf = rf << 2;
    int n  = flatf >> Ksh;
    int k0 = flatf & ((1 << Ksh) - 1);
    ushort4 ov;
    ov.x = f2bfu(vv.x); ov.y = f2bfu(vv.y); ov.z = f2bfu(vv.z); ov.w = f2bfu(vv.w);
    *(ushort4*)(db + swidx(n, k0, 1 << (Ksh - 5))) = ov;
}

__global__ __launch_bounds__(256) void concat3_k(
    const float* __restrict__ a, const float* __restrict__ b,
    const float* __restrict__ c, float* __restrict__ o)
{
    int i = blockIdx.x * 256 + threadIdx.x;
    o[i] = (i < 1024) ? a[i] : ((i < 2048) ? b[i - 1024] : c[i - 2048]);
}

__global__ __launch_bounds__(256) void reorder_w_k(
    const float* __restrict__ src, unsigned short* __restrict__ dst, int OC, int IC)
{
    int idx = blockIdx.x * 256 + threadIdx.x;
    if (idx >= OC * IC * 3) return;
    int k  = idx % 3;
    int ic = (idx / 3) % IC;
    int oc = idx / (3 * IC);
    dst[(oc * 3 + k) * IC + ic] = f2bfu(src[idx]);
}

// meanpool split: 256-block partial pass (16 rows each, all 1024 d) then a
// 16-block reduce. Old single-pass version ran on only 16 CUs pulling 16 MB.
__global__ __launch_bounds__(256) void meanpool_part_k(
    const float* __restrict__ h, float* __restrict__ part)
{
    int g = blockIdx.x;                 // g = b*64 + rblk
    int b = g >> 6, rblk = g & 63;
    const float4* base = (const float4*)(h + ((long long)b << 20)
                                           + ((long long)(rblk * 16) << 10));
    float4 s = {0.f, 0.f, 0.f, 0.f};
#pragma unroll
    for (int i = 0; i < 16; i++) {
        float4 v = base[i * 256 + threadIdx.x];
        s.x += v.x; s.y += v.y; s.z += v.z; s.w += v.w;
    }
    ((float4*)part)[g * 256 + threadIdx.x] = s;
}

__global__ __launch_bounds__(256) void meanpool_red_k(
    const float* __restrict__ part, float* __restrict__ pooled)
{
    int idx = blockIdx.x * 256 + threadIdx.x;   // 4096: b = idx>>10, d = idx&1023
    int b = idx >> 10, d = idx & 1023;
    const float* p = part + ((long long)(b * 64) << 10) + d;
    float s = 0.f;
#pragma unroll 8
    for (int r = 0; r < 64; r++) s += p[r << 10];
    pooled[idx] = s * (1.0f / 1024.0f);
}

__global__ __launch_bounds__(256) void fc_k(
    const float* __restrict__ p, const float* __restrict__ w,
    const float* __restrict__ fb, float* __restrict__ out)
{
    int b = blockIdx.x, t = threadIdx.x;
    float s = 0.f;
    for (int i = t; i < 1024; i += 256) s += p[(b << 10) + i] * w[i];
#pragma unroll
    for (int o = 32; o; o >>= 1) s += __shfl_down(s, o);
    __shared__ float red[4];
    if ((t & 63) == 0) red[t >> 6] = s;
    __syncthreads();
    if (t == 0) out[b] = red[0] + red[1] + red[2] + red[3] + fb[0];
}

// ---------------------------------------------------------------------------
extern "C" void kernel_launch(void* const* d_in, const int* in_sizes, int n_in,
                              void* d_out, int out_size, void* d_ws, size_t ws_size,
                              hipStream_t stream)
{
    const float* x    = (const float*)d_in[0];
    const float* c1w  = (const float*)d_in[1];
    const float* c1b  = (const float*)d_in[2];
    const float* c2w  = (const float*)d_in[3];
    const float* c2b  = (const float*)d_in[4];
    const float* lnAw = (const float*)d_in[5];
    const float* lnAb = (const float*)d_in[6];
    const float* qw   = (const float*)d_in[7];
    const float* qbi  = (const float*)d_in[8];
    const float* kw   = (const float*)d_in[9];
    const float* kbi  = (const float*)d_in[10];
    const float* vw   = (const float*)d_in[11];
    const float* vbi  = (const float*)d_in[12];
    const float* ow   = (const float*)d_in[13];
    const float* obi  = (const float*)d_in[14];
    const float* lnBw = (const float*)d_in[15];
    const float* lnBb = (const float*)d_in[16];
    const float* f1w  = (const float*)d_in[17];
    const float* f1b  = (const float*)d_in[18];
    const float* f2w  = (const float*)d_in[19];
    const float* f2b  = (const float*)d_in[20];
    const float* fcw  = (const float*)d_in[21];
    const float* fcb  = (const float*)d_in[22];
    float* out = (float*)d_out;

    float* ws = (float*)d_ws;
    typedef __hip_bfloat16 bf;
    typedef unsigned short us;
    float* h    = ws;                          // 4,194,304 f
    us* hn_b    = (us*)(ws + 4194304);         // 4M us (swizzled activations)
    us* qkv_b   = (us*)(ws + 6291456);         // [4096][3072] us row-major
    us* ff_b    = qkv_b;                       // [4096][2048] swizzled overlay
    us* wq_b    = (us*)(ws + 12582912);        // swizzled: q,k,v,o,f1,f2
    us* wo_b    = (us*)(ws + 14155776);
    us* wf1_b   = (us*)(ws + 14680064);
    us* wf2_b   = (us*)(ws + 15728640);
    us* xb      = (us*)(ws + 16777216);
    us* h1b     = (us*)(ws + 16912896);
    us* w1t_b   = (us*)(ws + 17963520);
    us* w2t_b   = (us*)(ws + 18012672);
    float* pooled = ws + 18799104;             // 4,096 f
    us* Vt      = (us*)(ws + 18803200);        // [4][1024 d][1024 t] us
    float* bqkv = ws + 20900352;               // 3,072 f
    float* mp_part = ws + 20903424;            // 262,144 f (meanpool partials)

    convert_k<<<dim3(257), 256, 0, stream>>>(x, xb, 65792);
    reorder_w_k<<<dim3(384),  256, 0, stream>>>(c1w, w1t_b, 512, 64);
    reorder_w_k<<<dim3(6144), 256, 0, stream>>>(c2w, w2t_b, 1024, 512);

    // conv1: M=4104, N=512, K=192 (LDS-staged kernel, row-remapped A)
    gemm_mfma_k<<<dim3(8, 33), 256, 0, stream>>>(
        (const bf*)xb, 1026, 1028LL * 64, 64, (const bf*)w1t_b,
        c1b, nullptr, nullptr, (bf*)h1b, 4104, 512, 192, 512, 0);
    // conv2: M=4096, N=1024, K=1536
    gemm_mfma_k<<<dim3(16, 32), 256, 0, stream>>>(
        (const bf*)h1b, 1024, 1026LL * 512, 512, (const bf*)w2t_b,
        c2b, nullptr, h, nullptr, 4096, 1024, 1536, 1024, 0);
    add_pos_k<<<dim3(16384), 256, 0, stream>>>(h);

    for (int l = 0; l < 4; l++) {
        long long wo  = (long long)l * 1048576;
        long long wo2 = (long long)l * 2097152;
        convert_layer_sw_k<<<dim3(8192), 256, 0, stream>>>(
            qw + wo, kw + wo, vw + wo, ow + wo, f1w + wo2, f2w + wo2, wq_b);
        concat3_k<<<dim3(12), 256, 0, stream>>>(qbi + l * 1024, kbi + l * 1024,
                                                vbi + l * 1024, bqkv);

        layernorm_k<<<dim3(4096), 256, 0, stream>>>(h, lnAw + l * 1024, lnAb + l * 1024, hn_b);
        // fused QKV: N=3072; Q,K swizzled to qkv_b; V transposed to Vt
        gemm_sw_k<<<dim3(48, 64), 64, 0, stream>>>(
            hn_b, wq_b, bqkv, nullptr, nullptr, qkv_b, nullptr, Vt, 2048,
            4096, 3072, 1024, 3072, 0);
        attn_mfma_k<<<dim3(8, 64), 256, 0, stream>>>(qkv_b, Vt, hn_b);
        // O-proj: out fp32 h += res
        gemm_sw_k<<<dim3(16, 64), 64, 0, stream>>>(
            hn_b, wo_b, obi + l * 1024, h, h, nullptr, nullptr, nullptr, 0,
            4096, 1024, 1024, 1024, 0);
        layernorm_k<<<dim3(4096), 256, 0, stream>>>(h, lnBw + l * 1024, lnBb + l * 1024, hn_b);
        // FF1: out swizzled bf16 (+relu)
        gemm_sw_k<<<dim3(32, 64), 64, 0, stream>>>(
            hn_b, wf1_b, f1b + l * 2048, nullptr, nullptr, nullptr, ff_b, nullptr, 0,
            4096, 2048, 1024, 2048, 1);
        // FF2: out fp32 h += res
        gemm_sw_k<<<dim3(16, 64), 64, 0, stream>>>(
            ff_b, wf2_b, f2b + l * 1024, h, h, nullptr, nullptr, nullptr, 0,
            4096, 1024, 2048, 1024, 0);
    }

    meanpool_part_k<<<dim3(256), 256, 0, stream>>>(h, mp_part);
    meanpool_red_k<<<dim3(16), 256, 0, stream>>>(mp_part, pooled);
    fc_k<<<dim3(4), 256, 0, stream>>>(pooled, fcw, fcb, out);
}

// Round 10
// 1109.905 us; speedup vs baseline: 1.4808x; 1.0109x over previous
//
#include <hip/hip_runtime.h>
#include <hip/hip_bf16.h>
#include <math.h>

// ---------------------------------------------------------------------------
// helpers
// ---------------------------------------------------------------------------
typedef __bf16 v8bf __attribute__((ext_vector_type(8)));
typedef float  v4f  __attribute__((ext_vector_type(4)));
typedef unsigned short v8us __attribute__((ext_vector_type(8)));

__device__ __forceinline__ unsigned short f2bfu(float f) {
    unsigned u = __builtin_bit_cast(unsigned, f);
    unsigned r = (u + 0x7fffu + ((u >> 16) & 1u)) >> 16;
    return (unsigned short)r;
}
__device__ __forceinline__ float bf2f(unsigned short u) {
    unsigned x = ((unsigned)u) << 16;
    return __builtin_bit_cast(float, x);
}

// fragment-swizzled element address: matrix [rows][K cols] stored so that a
// wave's 16x32 MFMA fragment is contiguous: sw(r,k) =
//   tile(r>>4, k>>5) * 512 + lane((k>>3)&3, r&15) * 8 + (k&7)
__device__ __forceinline__ long long swidx(int r, int k, int kt /*=K>>5*/) {
    return ((long long)((r >> 4) * kt + (k >> 5)) << 9)
         + (((k >> 3) & 3) << 7) + ((r & 15) << 3) + (k & 7);
}

#define GLDS16(g, s)                                                        \
    __builtin_amdgcn_global_load_lds(                                       \
        (const __attribute__((address_space(1))) void*)(g),                 \
        (__attribute__((address_space(3))) void*)(s), 16, 0, 0)

// ---------------------------------------------------------------------------
// SWIZZLED register-direct bf16 MFMA GEMM (no LDS, no barriers).
// A (M x K) and B (N x K) in fragment-swizzled layout (see swidx).
// 128-THREAD BLOCKS = 2 independent 64x64 wave tiles (wave w covers
// n0 = bx*128 + w*64). No inter-wave sharing or barriers; the two waves
// read the same A fragments -> L1/L2 hits.
//
// R9 established: with the L2-locality block mapping, FETCH drops to
// ~compulsory (72->35MB QKV) and the kernel falls onto an exposed-latency
// floor at ~4.5 resident waves/CU (Occupancy 14%, not VGPR-limited at 96).
// Hypothesis: residency is workgroup-count-capped; 2-wave blocks double
// waves/CU at constant wg/CU. Falsifiable via OccupancyPercent.
//
// Block mapping (R9, verified -37MB FETCH): 8 L2-sized regions
// (4 by-strips x 2 bx-strips) selected by bid&7; 4x4 micro-tiles inside,
// micro-rows major. Guard: nbx%8==0 && nby%16==0 (all grids qualify).
//
// Outputs: Cf (fp32,+res row-major) | Cb (bf16 row-major) | Csw (bf16
// swizzled for the next GEMM, K_consumer = N) ; cols >= ctcol0 (Ct!=null)
// go transposed to Ct (attention V^T). M mult 64, N mult 128, kt=K/32
// a multiple of 4 and >= 8 (kt = 32 or 64 here).
// ---------------------------------------------------------------------------
#define LOAD_CHUNK(R, C) do {                                               \
    const long long o_ = (long long)(C) << 9;                               \
    _Pragma("unroll")                                                       \
    for (int i_ = 0; i_ < 4; i_++) Ab[R][i_] = *(const v8bf*)(pa[i_] + o_); \
    _Pragma("unroll")                                                       \
    for (int j_ = 0; j_ < 4; j_++) Bb[R][j_] = *(const v8bf*)(pb[j_] + o_); \
} while (0)

#define MFMA_CHUNK(R) do {                                                  \
    _Pragma("unroll")                                                       \
    for (int i_ = 0; i_ < 4; i_++)                                          \
    _Pragma("unroll")                                                       \
    for (int j_ = 0; j_ < 4; j_++)                                          \
        acc[i_][j_] = __builtin_amdgcn_mfma_f32_16x16x32_bf16(              \
            Ab[R][i_], Bb[R][j_], acc[i_][j_], 0, 0, 0);                    \
} while (0)

__global__ __launch_bounds__(128, 2) void gemm_sw_k(
    const unsigned short* __restrict__ Asw,
    const unsigned short* __restrict__ Bsw,
    const float* __restrict__ bias,
    const float* __restrict__ res,
    float* __restrict__ Cf,
    unsigned short* __restrict__ Cb,
    unsigned short* __restrict__ Csw,
    unsigned short* __restrict__ Ct, int ctcol0,
    int M, int N, int K, int ldC, int relu)
{
    const int wv = threadIdx.x >> 6;   // n-half within block
    const int l  = threadIdx.x & 63;

    int bx = blockIdx.x, by = blockIdx.y;
    {
        int nbx = gridDim.x, nby = gridDim.y;
        if (((nbx & 7) == 0) && ((nby & 15) == 0)) {
            // L2-locality mapping: 8 XCD regions (4 by-strips x 2 bx-strips),
            // 4x4 micro-tiles inside, micro-rows major. Bijective.
            int bid   = by * nbx + bx;
            int xcd   = bid & 7;
            int local = bid >> 3;             // [0, nb/8)
            int rby = nby >> 2;               // region height (blocks)
            int rbx = nbx >> 1;               // region width
            int u   = local & 15;             // 4x4 micro-tile cell
            int mt  = local >> 4;             // micro-tile index
            int mtxc = rbx >> 2;              // micro-tiles per region row
            int mty = mt / mtxc;
            int mtx = mt - mty * mtxc;
            by = (xcd >> 1) * rby + (mty << 2) + (u >> 2);
            bx = (xcd & 1) * rbx + (mtx << 2) + (u & 3);
        } else {
            int nb = nbx * nby;
            if ((nb & 7) == 0) {              // fallback: old XCD swizzle
                int bid = by * nbx + bx;
                int nid = (bid & 7) * (nb >> 3) + (bid >> 3);
                by = nid / nbx;
                bx = nid - by * nbx;
            }
        }
    }
    const int m0 = by * 64;
    const int n0 = bx * 128 + wv * 64;
    const int r16 = l & 15;
    const int qb  = l >> 4;
    const int kt = K >> 5;

    // fragment base pointers: contiguous 16B per lane
    const unsigned short* pa[4];
#pragma unroll
    for (int i = 0; i < 4; i++)
        pa[i] = Asw + ((long long)(((m0 >> 4) + i) * kt) << 9) + l * 8;
    const unsigned short* pb[4];
#pragma unroll
    for (int j = 0; j < 4; j++)
        pb[j] = Bsw + ((long long)(((n0 >> 4) + j) * kt) << 9) + l * 8;

    v4f acc[4][4];
#pragma unroll
    for (int i = 0; i < 4; i++)
#pragma unroll
        for (int j = 0; j < 4; j++) acc[i][j] = (v4f){0.f, 0.f, 0.f, 0.f};

    v8bf Ab[4][4], Bb[4][4];

    // prologue: chunks 0,1,2 -> rings 0,1,2
    LOAD_CHUNK(0, 0);
    LOAD_CHUNK(1, 1);
    LOAD_CHUNK(2, 2);

    // steady state: straight-line, no branches, literal ring indices.
    int s = 0;
    for (; s < kt - 4; s += 4) {
        LOAD_CHUNK(3, s + 3); MFMA_CHUNK(0);
        LOAD_CHUNK(0, s + 4); MFMA_CHUNK(1);
        LOAD_CHUNK(1, s + 5); MFMA_CHUNK(2);
        LOAD_CHUNK(2, s + 6); MFMA_CHUNK(3);
    }
    // epilogue: s == kt-4; rings hold kt-4,kt-3,kt-2; load last chunk.
    LOAD_CHUNK(3, kt - 1);
    MFMA_CHUNK(0); MFMA_CHUNK(1); MFMA_CHUNK(2); MFMA_CHUNK(3);

    float bv[4];
#pragma unroll
    for (int j = 0; j < 4; j++) bv[j] = bias[n0 + 16 * j + r16];
    const int colbase = n0 + r16;
    const int nt = N >> 5;
#pragma unroll
    for (int i = 0; i < 4; i++) {
        int rowb = m0 + 16 * i + qb * 4;
#pragma unroll
        for (int j = 0; j < 4; j++) {
            int col = colbase + 16 * j;
            float v[4];
#pragma unroll
            for (int r = 0; r < 4; r++) v[r] = acc[i][j][r] + bv[j];
            if (Ct && col >= ctcol0) {
                ushort4 o;
                o.x = f2bfu(v[0]); o.y = f2bfu(v[1]);
                o.z = f2bfu(v[2]); o.w = f2bfu(v[3]);
                *(ushort4*)(Ct + ((long long)(rowb >> 10) << 20)
                            + (long long)(col - ctcol0) * 1024 + (rowb & 1023)) = o;
            } else if (Csw) {
#pragma unroll
                for (int r = 0; r < 4; r++) {
                    int row = rowb + r;
                    float vv = v[r];
                    if (relu) vv = fmaxf(vv, 0.f);
                    Csw[swidx(row, col, nt)] = f2bfu(vv);
                }
            } else {
#pragma unroll
                for (int r = 0; r < 4; r++) {
                    int row = rowb + r;
                    long long off = (long long)row * ldC + col;
                    float vv = v[r];
                    if (res)  vv += res[off];
                    if (relu) vv = fmaxf(vv, 0.f);
                    if (Cf) Cf[off] = vv;
                    if (Cb) ((unsigned short*)Cb)[off] = f2bfu(vv);
                }
            }
        }
    }
}

// ---------------------------------------------------------------------------
// LDS-staged GEMM (R5) — kept for the conv frontend (row-remapped A).
// ---------------------------------------------------------------------------
__global__ __launch_bounds__(256) void gemm_mfma_k(
    const __hip_bfloat16* __restrict__ A, int rpbA, long long bstrideA, int ldA,
    const __hip_bfloat16* __restrict__ B,
    const float* __restrict__ bias,
    const float* __restrict__ res,
    float* __restrict__ Cf,
    __hip_bfloat16* __restrict__ Cb,
    int M, int N, int K, int ldC, int relu)
{
    __shared__ __align__(16) __hip_bfloat16 As[2][8][64][8];
    __shared__ __align__(16) __hip_bfloat16 Bs[2][4][64][8];
    const int t  = threadIdx.x;
    const int w  = t >> 6;
    const int l  = t & 63;
    const int m0 = blockIdx.y * 128;
    const int n0 = blockIdx.x * 64;
    const int r16 = l & 15;
    const int qb  = l >> 4;
    const int wm = w >> 1, wn = w & 1;

    const __hip_bfloat16* gA[2];
#pragma unroll
    for (int tt = 0; tt < 2; tt++) {
        int arow = m0 + 16 * (2 * w + tt) + r16;
        gA[tt] = A + (long long)(arow / rpbA) * bstrideA
                   + (long long)(arow % rpbA) * ldA + qb * 8;
    }
    const __hip_bfloat16* gB = B + (long long)(n0 + 16 * w + r16) * K + qb * 8;

    v4f acc[4][2];
#pragma unroll
    for (int i = 0; i < 4; i++)
#pragma unroll
        for (int j = 0; j < 2; j++) acc[i][j] = (v4f){0.f, 0.f, 0.f, 0.f};

    GLDS16(gA[0], &As[0][2 * w + 0][0][0]);
    GLDS16(gA[1], &As[0][2 * w + 1][0][0]);
    GLDS16(gB,    &Bs[0][w][0][0]);
    __syncthreads();

    int cur = 0;
    for (int k0 = 32; k0 < K; k0 += 32) {
        v8bf af[4], bfr[2];
#pragma unroll
        for (int i = 0; i < 4; i++) af[i]  = *(const v8bf*)(&As[cur][4 * wm + i][l][0]);
#pragma unroll
        for (int j = 0; j < 2; j++) bfr[j] = *(const v8bf*)(&Bs[cur][2 * wn + j][l][0]);
        GLDS16(gA[0] + k0, &As[cur ^ 1][2 * w + 0][0][0]);
        GLDS16(gA[1] + k0, &As[cur ^ 1][2 * w + 1][0][0]);
        GLDS16(gB + k0,    &Bs[cur ^ 1][w][0][0]);
#pragma unroll
        for (int i = 0; i < 4; i++)
#pragma unroll
            for (int j = 0; j < 2; j++)
                acc[i][j] = __builtin_amdgcn_mfma_f32_16x16x32_bf16(
                    af[i], bfr[j], acc[i][j], 0, 0, 0);
        __syncthreads();
        cur ^= 1;
    }
    {
        v8bf af[4], bfr[2];
#pragma unroll
        for (int i = 0; i < 4; i++) af[i]  = *(const v8bf*)(&As[cur][4 * wm + i][l][0]);
#pragma unroll
        for (int j = 0; j < 2; j++) bfr[j] = *(const v8bf*)(&Bs[cur][2 * wn + j][l][0]);
#pragma unroll
        for (int i = 0; i < 4; i++)
#pragma unroll
            for (int j = 0; j < 2; j++)
                acc[i][j] = __builtin_amdgcn_mfma_f32_16x16x32_bf16(
                    af[i], bfr[j], acc[i][j], 0, 0, 0);
    }

    float bv[2];
#pragma unroll
    for (int j = 0; j < 2; j++) bv[j] = bias[n0 + 32 * wn + 16 * j + r16];
    const int colbase = n0 + 32 * wn + r16;
#pragma unroll
    for (int i = 0; i < 4; i++) {
        int rowb = m0 + 64 * wm + 16 * i + qb * 4;
#pragma unroll
        for (int j = 0; j < 2; j++) {
            int col = colbase + 16 * j;
#pragma unroll
            for (int r = 0; r < 4; r++) {
                int row = rowb + r;
                if (row >= M) continue;
                long long off = (long long)row * ldC + col;
                float vv = acc[i][j][r] + bv[j];
                if (res)  vv += res[off];
                if (relu) vv = fmaxf(vv, 0.f);
                if (Cf) Cf[off] = vv;
                if (Cb) ((unsigned short*)Cb)[off] = f2bfu(vv);
            }
        }
    }
}

// ---------------------------------------------------------------------------
// MFMA softsign attention, K/V DOUBLE-BUFFERED with prefetch-before-compute.
// Output written in SWIZZLED layout (K=1024 -> 32).
// LDS layout (us): P/out [0, 9216) (overlays the dead Q region after the
// prologue), KV buf0 [9216, 17408), KV buf1 [17408, 25600); K at base,
// V at base+4096 within each buf. The old loop was fully serial
// (GLDS; sync; compute; sync -> full ~500cy latency exposed / iter);
// now iter t+1's 4 GLDS are issued before iter t's compute, so the
// end-of-iter __syncthreads drain covers only (latency - compute).
// Extra barrier after the qf register loads: P (base 0) overlays Q, and
// wave w's P rows [2304w, 2304w+2304) overlap wave w+1's Q frags.
// ---------------------------------------------------------------------------
__global__ __launch_bounds__(256) void attn_mfma_k(
    const unsigned short* __restrict__ QKV,
    const unsigned short* __restrict__ Vt,
    unsigned short* __restrict__ Osw)
{
    __shared__ __align__(16) unsigned short lds[25600];
    const int t = threadIdx.x, w = t >> 6, l = t & 63;
    const int bh = blockIdx.y, b = bh >> 4, h = bh & 15;
    const int s0 = blockIdx.x << 7;
    const int r16 = l & 15, q4 = l >> 4;
    const long long qrow0 = (long long)(b << 10) + s0;
    const int hoff = h << 6;

#define LOAD_KV(T0, KVW) do {                                               \
    _Pragma("unroll")                                                       \
    for (int rr_ = 0; rr_ < 2; rr_++) {                                     \
        int r_ = 2 * w + rr_, kk_ = r_ >> 2, j_ = r_ & 3;                   \
        const unsigned short* gk_ = QKV                                     \
            + ((long long)(b << 10) + (T0) + 16 * j_ + r16) * 3072          \
            + 1024 + hoff + 32 * kk_ + q4 * 8;                              \
        GLDS16(gk_, &lds[(KVW) + r_ * 512]);                                \
        const unsigned short* gv_ = Vt + ((long long)b << 20)               \
            + (long long)(hoff + 16 * j_ + r16) * 1024 + (T0)               \
            + 32 * kk_ + q4 * 8;                                            \
        GLDS16(gv_, &lds[(KVW) + 4096 + r_ * 512]);                         \
    }                                                                       \
} while (0)

    // prologue: Q -> [0,8192) and first K/V tile -> buf0
#pragma unroll
    for (int mi = 0; mi < 2; mi++)
#pragma unroll
        for (int kk = 0; kk < 2; kk++) {
            const unsigned short* g = QKV + (qrow0 + 32 * w + 16 * mi + r16) * 3072
                                      + hoff + 32 * kk + q4 * 8;
            GLDS16(g, &lds[(w * 4 + mi * 2 + kk) * 512]);
        }
    LOAD_KV(0, 9216);
    __syncthreads();
    v8bf qf[2][2];
#pragma unroll
    for (int mi = 0; mi < 2; mi++)
#pragma unroll
        for (int kk = 0; kk < 2; kk++)
            qf[mi][kk] = *(const v8bf*)&lds[(w * 4 + mi * 2 + kk) * 512 + l * 8];
    __syncthreads();   // all qf in regs before P overwrites the Q region

    v4f oacc[2][4];
#pragma unroll
    for (int i = 0; i < 2; i++)
#pragma unroll
        for (int j = 0; j < 4; j++) oacc[i][j] = (v4f){0.f, 0.f, 0.f, 0.f};

    int cur = 0;
    for (int it = 0; it < 16; ++it) {
        const int kvr = 9216 + cur * 8192;
        if (it < 15) LOAD_KV((it + 1) * 64, 9216 + (cur ^ 1) * 8192);

        v8bf kf[2][4];
#pragma unroll
        for (int kk = 0; kk < 2; kk++)
#pragma unroll
            for (int j = 0; j < 4; j++)
                kf[kk][j] = *(const v8bf*)&lds[kvr + (kk * 4 + j) * 512 + l * 8];
        v4f sc[2][4];
#pragma unroll
        for (int i = 0; i < 2; i++)
#pragma unroll
            for (int j = 0; j < 4; j++) sc[i][j] = (v4f){0.f, 0.f, 0.f, 0.f};
#pragma unroll
        for (int kk = 0; kk < 2; kk++)
#pragma unroll
            for (int mi = 0; mi < 2; mi++)
#pragma unroll
                for (int j = 0; j < 4; j++)
                    sc[mi][j] = __builtin_amdgcn_mfma_f32_16x16x32_bf16(
                        qf[mi][kk], kf[kk][j], sc[mi][j], 0, 0, 0);

#pragma unroll
        for (int mi = 0; mi < 2; mi++)
#pragma unroll
            for (int j = 0; j < 4; j++)
#pragma unroll
                for (int r = 0; r < 4; r++) {
                    float v = sc[mi][j][r] * 0.125f;
                    float p = v * __builtin_amdgcn_rcpf(1.0f + fabsf(v));
                    lds[(32 * w + 16 * mi + q4 * 4 + r) * 72 + 16 * j + r16] = f2bfu(p);
                }

        v8bf pf[2][2], vf[2][4];
#pragma unroll
        for (int mi = 0; mi < 2; mi++)
#pragma unroll
            for (int kk = 0; kk < 2; kk++)
                pf[mi][kk] = *(const v8bf*)&lds[(32 * w + 16 * mi + r16) * 72
                                                + 32 * kk + q4 * 8];
#pragma unroll
        for (int kk = 0; kk < 2; kk++)
#pragma unroll
            for (int j = 0; j < 4; j++)
                vf[kk][j] = *(const v8bf*)&lds[kvr + 4096 + (kk * 4 + j) * 512 + l * 8];
#pragma unroll
        for (int kk = 0; kk < 2; kk++)
#pragma unroll
            for (int mi = 0; mi < 2; mi++)
#pragma unroll
                for (int j = 0; j < 4; j++)
                    oacc[mi][j] = __builtin_amdgcn_mfma_f32_16x16x32_bf16(
                        pf[mi][kk], vf[kk][j], oacc[mi][j], 0, 0, 0);
        __syncthreads();
        cur ^= 1;
    }
#undef LOAD_KV

#pragma unroll
    for (int mi = 0; mi < 2; mi++)
#pragma unroll
        for (int j = 0; j < 4; j++)
#pragma unroll
            for (int r = 0; r < 4; r++)
                lds[(32 * w + 16 * mi + q4 * 4 + r) * 72 + 16 * j + r16] =
                    f2bfu(oacc[mi][j][r]);
    __syncthreads();
    {
        int row = t >> 1, ch = (t & 1) << 5;
        int grow = (int)qrow0 + row;
#pragma unroll
        for (int i = 0; i < 4; i++) {
            int c0 = hoff + ch + 8 * i;
            v8us vv = *(const v8us*)&lds[row * 72 + ch + 8 * i];
            *(v8us*)(Osw + swidx(grow, c0, 32)) = vv;
        }
    }
}

// ---------------------------------------------------------------------------
// LayerNorm (torch-style), output bf16 in SWIZZLED layout (K=1024).
// ---------------------------------------------------------------------------
__global__ __launch_bounds__(256) void layernorm_k(
    const float* __restrict__ x, const float* __restrict__ w,
    const float* __restrict__ b, unsigned short* __restrict__ ysw)
{
    int row = blockIdx.x;
    int t = threadIdx.x;
    float4 v = ((const float4*)(x + ((long long)row << 10)))[t];
    float s = v.x + v.y + v.z + v.w;
#pragma unroll
    for (int o = 32; o; o >>= 1) s += __shfl_down(s, o);
    __shared__ float red[4];
    __shared__ float red2[4];
    int wid = t >> 6, lane = t & 63;
    if (lane == 0) red[wid] = s;
    __syncthreads();
    float mean = (red[0] + red[1] + red[2] + red[3]) * (1.0f / 1024.0f);
    float dx = v.x - mean, dy = v.y - mean, dz = v.z - mean, dw = v.w - mean;
    float sq = dx * dx + dy * dy + dz * dz + dw * dw;
#pragma unroll
    for (int o = 32; o; o >>= 1) sq += __shfl_down(sq, o);
    if (lane == 0) red2[wid] = sq;
    __syncthreads();
    float var = (red2[0] + red2[1] + red2[2] + red2[3]) * (1.0f / 1023.0f);
    float inv = 1.0f / (sqrtf(var) + 1e-6f);
    float4 W  = ((const float4*)w)[t];
    float4 Bv = ((const float4*)b)[t];
    ushort4 o;
    o.x = f2bfu(W.x * (dx * inv) + Bv.x);
    o.y = f2bfu(W.y * (dy * inv) + Bv.y);
    o.z = f2bfu(W.z * (dz * inv) + Bv.z);
    o.w = f2bfu(W.w * (dw * inv) + Bv.w);
    int c0 = t << 2;
    *(ushort4*)(ysw + swidx(row, c0, 32)) = o;
}

// ---------------------------------------------------------------------------
__global__ __launch_bounds__(256) void add_pos_k(float* __restrict__ h)
{
    int idx = blockIdx.x * 256 + threadIdx.x;
    int d = idx & 1023;
    int s = (idx >> 10) & 1023;
    int e = d & ~1;
    float div = expf(-9.210340371976184f * (float)e * (1.0f / 1024.0f));
    float arg = (float)s * div;
    float pe = (d & 1) ? cosf(arg) : sinf(arg);
    h[idx] += pe;
}

__global__ __launch_bounds__(256) void convert_k(
    const float* __restrict__ src, unsigned short* __restrict__ dst, int n4)
{
    int i = blockIdx.x * 256 + threadIdx.x;
    if (i >= n4) return;
    float4 v = ((const float4*)src)[i];
    ushort4 o;
    o.x = f2bfu(v.x); o.y = f2bfu(v.y); o.z = f2bfu(v.z); o.w = f2bfu(v.w);
    ((ushort4*)dst)[i] = o;
}

// Layer weights fp32 row-major -> bf16 SWIZZLED, all 6 matrices, one launch.
// dst layout (us): q,k,v,o (1M each), f1 (2M), f2 (2M) — contiguous.
__global__ __launch_bounds__(256) void convert_layer_sw_k(
    const float* __restrict__ q, const float* __restrict__ k,
    const float* __restrict__ v, const float* __restrict__ o,
    const float* __restrict__ f1, const float* __restrict__ f2,
    unsigned short* __restrict__ dst)
{
    int idx = blockIdx.x * 256 + threadIdx.x;   // float4 index, [0, 2M)
    const float* src;
    unsigned short* db;
    int Ksh, rf;
    if (idx < 0x100000) {
        int region = idx >> 18;
        rf = idx & 0x3FFFF;
        src = (region == 0) ? q : (region == 1) ? k : (region == 2) ? v : o;
        db = dst + ((long long)region << 20);
        Ksh = 10;
    } else if (idx < 0x180000) {
        rf = idx - 0x100000; src = f1; db = dst + (4LL << 20); Ksh = 10;
    } else {
        rf = idx - 0x180000; src = f2; db = dst + (6LL << 20); Ksh = 11;
    }
    float4 vv = ((const float4*)src)[rf];
    int flatf = rf << 2;
    int n  = flatf >> Ksh;
    int k0 = flatf & ((1 << Ksh) - 1);
    ushort4 ov;
    ov.x = f2bfu(vv.x); ov.y = f2bfu(vv.y); ov.z = f2bfu(vv.z); ov.w = f2bfu(vv.w);
    *(ushort4*)(db + swidx(n, k0, 1 << (Ksh - 5))) = ov;
}

__global__ __launch_bounds__(256) void concat3_k(
    const float* __restrict__ a, const float* __restrict__ b,
    const float* __restrict__ c, float* __restrict__ o)
{
    int i = blockIdx.x * 256 + threadIdx.x;
    o[i] = (i < 1024) ? a[i] : ((i < 2048) ? b[i - 1024] : c[i - 2048]);
}

__global__ __launch_bounds__(256) void reorder_w_k(
    const float* __restrict__ src, unsigned short* __restrict__ dst, int OC, int IC)
{
    int idx = blockIdx.x * 256 + threadIdx.x;
    if (idx >= OC * IC * 3) return;
    int k  = idx % 3;
    int ic = (idx / 3) % IC;
    int oc = idx / (3 * IC);
    dst[(oc * 3 + k) * IC + ic] = f2bfu(src[idx]);
}

// meanpool split: 256-block partial pass (16 rows each, all 1024 d) then a
// 16-block reduce. Old single-pass version ran on only 16 CUs pulling 16 MB.
__global__ __launch_bounds__(256) void meanpool_part_k(
    const float* __restrict__ h, float* __restrict__ part)
{
    int g = blockIdx.x;                 // g = b*64 + rblk
    int b = g >> 6, rblk = g & 63;
    const float4* base = (const float4*)(h + ((long long)b << 20)
                                           + ((long long)(rblk * 16) << 10));
    float4 s = {0.f, 0.f, 0.f, 0.f};
#pragma unroll
    for (int i = 0; i < 16; i++) {
        float4 v = base[i * 256 + threadIdx.x];
        s.x += v.x; s.y += v.y; s.z += v.z; s.w += v.w;
    }
    ((float4*)part)[g * 256 + threadIdx.x] = s;
}

__global__ __launch_bounds__(256) void meanpool_red_k(
    const float* __restrict__ part, float* __restrict__ pooled)
{
    int idx = blockIdx.x * 256 + threadIdx.x;   // 4096: b = idx>>10, d = idx&1023
    int b = idx >> 10, d = idx & 1023;
    const float* p = part + ((long long)(b * 64) << 10) + d;
    float s = 0.f;
#pragma unroll 8
    for (int r = 0; r < 64; r++) s += p[r << 10];
    pooled[idx] = s * (1.0f / 1024.0f);
}

__global__ __launch_bounds__(256) void fc_k(
    const float* __restrict__ p, const float* __restrict__ w,
    const float* __restrict__ fb, float* __restrict__ out)
{
    int b = blockIdx.x, t = threadIdx.x;
    float s = 0.f;
    for (int i = t; i < 1024; i += 256) s += p[(b << 10) + i] * w[i];
#pragma unroll
    for (int o = 32; o; o >>= 1) s += __shfl_down(s, o);
    __shared__ float red[4];
    if ((t & 63) == 0) red[t >> 6] = s;
    __syncthreads();
    if (t == 0) out[b] = red[0] + red[1] + red[2] + red[3] + fb[0];
}

// ---------------------------------------------------------------------------
extern "C" void kernel_launch(void* const* d_in, const int* in_sizes, int n_in,
                              void* d_out, int out_size, void* d_ws, size_t ws_size,
                              hipStream_t stream)
{
    const float* x    = (const float*)d_in[0];
    const float* c1w  = (const float*)d_in[1];
    const float* c1b  = (const float*)d_in[2];
    const float* c2w  = (const float*)d_in[3];
    const float* c2b  = (const float*)d_in[4];
    const float* lnAw = (const float*)d_in[5];
    const float* lnAb = (const float*)d_in[6];
    const float* qw   = (const float*)d_in[7];
    const float* qbi  = (const float*)d_in[8];
    const float* kw   = (const float*)d_in[9];
    const float* kbi  = (const float*)d_in[10];
    const float* vw   = (const float*)d_in[11];
    const float* vbi  = (const float*)d_in[12];
    const float* ow   = (const float*)d_in[13];
    const float* obi  = (const float*)d_in[14];
    const float* lnBw = (const float*)d_in[15];
    const float* lnBb = (const float*)d_in[16];
    const float* f1w  = (const float*)d_in[17];
    const float* f1b  = (const float*)d_in[18];
    const float* f2w  = (const float*)d_in[19];
    const float* f2b  = (const float*)d_in[20];
    const float* fcw  = (const float*)d_in[21];
    const float* fcb  = (const float*)d_in[22];
    float* out = (float*)d_out;

    float* ws = (float*)d_ws;
    typedef __hip_bfloat16 bf;
    typedef unsigned short us;
    float* h    = ws;                          // 4,194,304 f
    us* hn_b    = (us*)(ws + 4194304);         // 4M us (swizzled activations)
    us* qkv_b   = (us*)(ws + 6291456);         // [4096][3072] us row-major
    us* ff_b    = qkv_b;                       // [4096][2048] swizzled overlay
    us* wq_b    = (us*)(ws + 12582912);        // swizzled: q,k,v,o,f1,f2
    us* wo_b    = (us*)(ws + 14155776);
    us* wf1_b   = (us*)(ws + 14680064);
    us* wf2_b   = (us*)(ws + 15728640);
    us* xb      = (us*)(ws + 16777216);
    us* h1b     = (us*)(ws + 16912896);
    us* w1t_b   = (us*)(ws + 17963520);
    us* w2t_b   = (us*)(ws + 18012672);
    float* pooled = ws + 18799104;             // 4,096 f
    us* Vt      = (us*)(ws + 18803200);        // [4][1024 d][1024 t] us
    float* bqkv = ws + 20900352;               // 3,072 f
    float* mp_part = ws + 20903424;            // 262,144 f (meanpool partials)

    convert_k<<<dim3(257), 256, 0, stream>>>(x, xb, 65792);
    reorder_w_k<<<dim3(384),  256, 0, stream>>>(c1w, w1t_b, 512, 64);
    reorder_w_k<<<dim3(6144), 256, 0, stream>>>(c2w, w2t_b, 1024, 512);

    // conv1: M=4104, N=512, K=192 (LDS-staged kernel, row-remapped A)
    gemm_mfma_k<<<dim3(8, 33), 256, 0, stream>>>(
        (const bf*)xb, 1026, 1028LL * 64, 64, (const bf*)w1t_b,
        c1b, nullptr, nullptr, (bf*)h1b, 4104, 512, 192, 512, 0);
    // conv2: M=4096, N=1024, K=1536
    gemm_mfma_k<<<dim3(16, 32), 256, 0, stream>>>(
        (const bf*)h1b, 1024, 1026LL * 512, 512, (const bf*)w2t_b,
        c2b, nullptr, h, nullptr, 4096, 1024, 1536, 1024, 0);
    add_pos_k<<<dim3(16384), 256, 0, stream>>>(h);

    for (int l = 0; l < 4; l++) {
        long long wo  = (long long)l * 1048576;
        long long wo2 = (long long)l * 2097152;
        convert_layer_sw_k<<<dim3(8192), 256, 0, stream>>>(
            qw + wo, kw + wo, vw + wo, ow + wo, f1w + wo2, f2w + wo2, wq_b);
        concat3_k<<<dim3(12), 256, 0, stream>>>(qbi + l * 1024, kbi + l * 1024,
                                                vbi + l * 1024, bqkv);

        layernorm_k<<<dim3(4096), 256, 0, stream>>>(h, lnAw + l * 1024, lnAb + l * 1024, hn_b);
        // fused QKV: N=3072; Q,K swizzled to qkv_b; V transposed to Vt
        gemm_sw_k<<<dim3(24, 64), 128, 0, stream>>>(
            hn_b, wq_b, bqkv, nullptr, nullptr, qkv_b, nullptr, Vt, 2048,
            4096, 3072, 1024, 3072, 0);
        attn_mfma_k<<<dim3(8, 64), 256, 0, stream>>>(qkv_b, Vt, hn_b);
        // O-proj: out fp32 h += res
        gemm_sw_k<<<dim3(8, 64), 128, 0, stream>>>(
            hn_b, wo_b, obi + l * 1024, h, h, nullptr, nullptr, nullptr, 0,
            4096, 1024, 1024, 1024, 0);
        layernorm_k<<<dim3(4096), 256, 0, stream>>>(h, lnBw + l * 1024, lnBb + l * 1024, hn_b);
        // FF1: out swizzled bf16 (+relu)
        gemm_sw_k<<<dim3(16, 64), 128, 0, stream>>>(
            hn_b, wf1_b, f1b + l * 2048, nullptr, nullptr, nullptr, ff_b, nullptr, 0,
            4096, 2048, 1024, 2048, 1);
        // FF2: out fp32 h += res
        gemm_sw_k<<<dim3(8, 64), 128, 0, stream>>>(
            ff_b, wf2_b, f2b + l * 1024, h, h, nullptr, nullptr, nullptr, 0,
            4096, 1024, 2048, 1024, 0);
    }

    meanpool_part_k<<<dim3(256), 256, 0, stream>>>(h, mp_part);
    meanpool_red_k<<<dim3(16), 256, 0, stream>>>(mp_part, pooled);
    fc_k<<<dim3(4), 256, 0, stream>>>(pooled, fcw, fcb, out);
}

// Round 11
// 1089.989 us; speedup vs baseline: 1.5079x; 1.0183x over previous
//
#include <hip/hip_runtime.h>
#include <hip/hip_bf16.h>
#include <math.h>

// ---------------------------------------------------------------------------
// helpers
// ---------------------------------------------------------------------------
typedef __bf16 v8bf __attribute__((ext_vector_type(8)));
typedef float  v4f  __attribute__((ext_vector_type(4)));
typedef unsigned short v8us __attribute__((ext_vector_type(8)));

__device__ __forceinline__ unsigned short f2bfu(float f) {
    unsigned u = __builtin_bit_cast(unsigned, f);
    unsigned r = (u + 0x7fffu + ((u >> 16) & 1u)) >> 16;
    return (unsigned short)r;
}
__device__ __forceinline__ float bf2f(unsigned short u) {
    unsigned x = ((unsigned)u) << 16;
    return __builtin_bit_cast(float, x);
}

// fragment-swizzled element address: matrix [rows][K cols] stored so that a
// wave's 16x32 MFMA fragment is contiguous: sw(r,k) =
//   tile(r>>4, k>>5) * 512 + lane((k>>3)&3, r&15) * 8 + (k&7)
__device__ __forceinline__ long long swidx(int r, int k, int kt /*=K>>5*/) {
    return ((long long)((r >> 4) * kt + (k >> 5)) << 9)
         + (((k >> 3) & 3) << 7) + ((r & 15) << 3) + (k & 7);
}

#define GLDS16(g, s)                                                        \
    __builtin_amdgcn_global_load_lds(                                       \
        (const __attribute__((address_space(1))) void*)(g),                 \
        (__attribute__((address_space(3))) void*)(s), 16, 0, 0)

// ---------------------------------------------------------------------------
// SWIZZLED register-direct bf16 MFMA GEMM (no LDS, no barriers).
// A (M x K) and B (N x K) in fragment-swizzled layout (see swidx).
// ONE WAVE PER BLOCK (64 threads), wave tile 64x64 (R9 config — R10's
// 128-thread variant regressed FF1 48.3 vs <44.8 and dropped occupancy).
// R4 branch-free depth-4 ring body (compiler collapses it; at the ~490
// GF/s latency floor this is accepted — R1-R10 exhausted schedule levers).
//
// Block mapping (R9, verified: QKV FETCH 72->35MB): 8 L2-sized regions
// (4 by-strips x 2 bx-strips) selected by bid&7; 4x4 micro-tiles inside,
// micro-rows major. Guard: nbx%8==0 && nby%16==0 (all grids qualify).
//
// Outputs: Cf (fp32,+res row-major) | Cb (bf16 row-major) | Csw (bf16
// swizzled for the next GEMM, K_consumer = N) ; cols >= ctcol0 (Ct!=null)
// go transposed to Ct (attention V^T). M,N multiples of 64, kt=K/32
// a multiple of 4 and >= 8 (kt = 32, 48 or 64 here).
// ---------------------------------------------------------------------------
#define LOAD_CHUNK(R, C) do {                                               \
    const long long o_ = (long long)(C) << 9;                               \
    _Pragma("unroll")                                                       \
    for (int i_ = 0; i_ < 4; i_++) Ab[R][i_] = *(const v8bf*)(pa[i_] + o_); \
    _Pragma("unroll")                                                       \
    for (int j_ = 0; j_ < 4; j_++) Bb[R][j_] = *(const v8bf*)(pb[j_] + o_); \
} while (0)

#define MFMA_CHUNK(R) do {                                                  \
    _Pragma("unroll")                                                       \
    for (int i_ = 0; i_ < 4; i_++)                                          \
    _Pragma("unroll")                                                       \
    for (int j_ = 0; j_ < 4; j_++)                                          \
        acc[i_][j_] = __builtin_amdgcn_mfma_f32_16x16x32_bf16(              \
            Ab[R][i_], Bb[R][j_], acc[i_][j_], 0, 0, 0);                    \
} while (0)

__global__ __launch_bounds__(64, 2) void gemm_sw_k(
    const unsigned short* __restrict__ Asw,
    const unsigned short* __restrict__ Bsw,
    const float* __restrict__ bias,
    const float* __restrict__ res,
    float* __restrict__ Cf,
    unsigned short* __restrict__ Cb,
    unsigned short* __restrict__ Csw,
    unsigned short* __restrict__ Ct, int ctcol0,
    int M, int N, int K, int ldC, int relu)
{
    const int l = threadIdx.x;

    int bx = blockIdx.x, by = blockIdx.y;
    {
        int nbx = gridDim.x, nby = gridDim.y;
        if (((nbx & 7) == 0) && ((nby & 15) == 0)) {
            // L2-locality mapping: 8 XCD regions (4 by-strips x 2 bx-strips),
            // 4x4 micro-tiles inside, micro-rows major. Bijective.
            int bid   = by * nbx + bx;
            int xcd   = bid & 7;
            int local = bid >> 3;             // [0, nb/8)
            int rby = nby >> 2;               // region height (blocks)
            int rbx = nbx >> 1;               // region width
            int u   = local & 15;             // 4x4 micro-tile cell
            int mt  = local >> 4;             // micro-tile index
            int mtxc = rbx >> 2;              // micro-tiles per region row
            int mty = mt / mtxc;
            int mtx = mt - mty * mtxc;
            by = (xcd >> 1) * rby + (mty << 2) + (u >> 2);
            bx = (xcd & 1) * rbx + (mtx << 2) + (u & 3);
        } else {
            int nb = nbx * nby;
            if ((nb & 7) == 0) {              // fallback: old XCD swizzle
                int bid = by * nbx + bx;
                int nid = (bid & 7) * (nb >> 3) + (bid >> 3);
                by = nid / nbx;
                bx = nid - by * nbx;
            }
        }
    }
    const int m0 = by * 64;
    const int n0 = bx * 64;
    const int r16 = l & 15;
    const int qb  = l >> 4;
    const int kt = K >> 5;

    // fragment base pointers: contiguous 16B per lane
    const unsigned short* pa[4];
#pragma unroll
    for (int i = 0; i < 4; i++)
        pa[i] = Asw + ((long long)(((m0 >> 4) + i) * kt) << 9) + l * 8;
    const unsigned short* pb[4];
#pragma unroll
    for (int j = 0; j < 4; j++)
        pb[j] = Bsw + ((long long)(((n0 >> 4) + j) * kt) << 9) + l * 8;

    v4f acc[4][4];
#pragma unroll
    for (int i = 0; i < 4; i++)
#pragma unroll
        for (int j = 0; j < 4; j++) acc[i][j] = (v4f){0.f, 0.f, 0.f, 0.f};

    v8bf Ab[4][4], Bb[4][4];

    // prologue: chunks 0,1,2 -> rings 0,1,2
    LOAD_CHUNK(0, 0);
    LOAD_CHUNK(1, 1);
    LOAD_CHUNK(2, 2);

    // steady state: straight-line, no branches, literal ring indices.
    int s = 0;
    for (; s < kt - 4; s += 4) {
        LOAD_CHUNK(3, s + 3); MFMA_CHUNK(0);
        LOAD_CHUNK(0, s + 4); MFMA_CHUNK(1);
        LOAD_CHUNK(1, s + 5); MFMA_CHUNK(2);
        LOAD_CHUNK(2, s + 6); MFMA_CHUNK(3);
    }
    // epilogue: s == kt-4; rings hold kt-4,kt-3,kt-2; load last chunk.
    LOAD_CHUNK(3, kt - 1);
    MFMA_CHUNK(0); MFMA_CHUNK(1); MFMA_CHUNK(2); MFMA_CHUNK(3);

    float bv[4];
#pragma unroll
    for (int j = 0; j < 4; j++) bv[j] = bias[n0 + 16 * j + r16];
    const int colbase = n0 + r16;
    const int nt = N >> 5;
#pragma unroll
    for (int i = 0; i < 4; i++) {
        int rowb = m0 + 16 * i + qb * 4;
#pragma unroll
        for (int j = 0; j < 4; j++) {
            int col = colbase + 16 * j;
            float v[4];
#pragma unroll
            for (int r = 0; r < 4; r++) v[r] = acc[i][j][r] + bv[j];
            if (Ct && col >= ctcol0) {
                ushort4 o;
                o.x = f2bfu(v[0]); o.y = f2bfu(v[1]);
                o.z = f2bfu(v[2]); o.w = f2bfu(v[3]);
                *(ushort4*)(Ct + ((long long)(rowb >> 10) << 20)
                            + (long long)(col - ctcol0) * 1024 + (rowb & 1023)) = o;
            } else if (Csw) {
#pragma unroll
                for (int r = 0; r < 4; r++) {
                    int row = rowb + r;
                    float vv = v[r];
                    if (relu) vv = fmaxf(vv, 0.f);
                    Csw[swidx(row, col, nt)] = f2bfu(vv);
                }
            } else {
#pragma unroll
                for (int r = 0; r < 4; r++) {
                    int row = rowb + r;
                    long long off = (long long)row * ldC + col;
                    float vv = v[r];
                    if (res)  vv += res[off];
                    if (relu) vv = fmaxf(vv, 0.f);
                    if (Cf) Cf[off] = vv;
                    if (Cb) ((unsigned short*)Cb)[off] = f2bfu(vv);
                }
            }
        }
    }
}

// ---------------------------------------------------------------------------
// LDS-staged GEMM — kept ONLY for conv1 (M=4104 not a multiple of 64).
// ---------------------------------------------------------------------------
__global__ __launch_bounds__(256) void gemm_mfma_k(
    const __hip_bfloat16* __restrict__ A, int rpbA, long long bstrideA, int ldA,
    const __hip_bfloat16* __restrict__ B,
    const float* __restrict__ bias,
    const float* __restrict__ res,
    float* __restrict__ Cf,
    __hip_bfloat16* __restrict__ Cb,
    int M, int N, int K, int ldC, int relu)
{
    __shared__ __align__(16) __hip_bfloat16 As[2][8][64][8];
    __shared__ __align__(16) __hip_bfloat16 Bs[2][4][64][8];
    const int t  = threadIdx.x;
    const int w  = t >> 6;
    const int l  = t & 63;
    const int m0 = blockIdx.y * 128;
    const int n0 = blockIdx.x * 64;
    const int r16 = l & 15;
    const int qb  = l >> 4;
    const int wm = w >> 1, wn = w & 1;

    const __hip_bfloat16* gA[2];
#pragma unroll
    for (int tt = 0; tt < 2; tt++) {
        int arow = m0 + 16 * (2 * w + tt) + r16;
        gA[tt] = A + (long long)(arow / rpbA) * bstrideA
                   + (long long)(arow % rpbA) * ldA + qb * 8;
    }
    const __hip_bfloat16* gB = B + (long long)(n0 + 16 * w + r16) * K + qb * 8;

    v4f acc[4][2];
#pragma unroll
    for (int i = 0; i < 4; i++)
#pragma unroll
        for (int j = 0; j < 2; j++) acc[i][j] = (v4f){0.f, 0.f, 0.f, 0.f};

    GLDS16(gA[0], &As[0][2 * w + 0][0][0]);
    GLDS16(gA[1], &As[0][2 * w + 1][0][0]);
    GLDS16(gB,    &Bs[0][w][0][0]);
    __syncthreads();

    int cur = 0;
    for (int k0 = 32; k0 < K; k0 += 32) {
        v8bf af[4], bfr[2];
#pragma unroll
        for (int i = 0; i < 4; i++) af[i]  = *(const v8bf*)(&As[cur][4 * wm + i][l][0]);
#pragma unroll
        for (int j = 0; j < 2; j++) bfr[j] = *(const v8bf*)(&Bs[cur][2 * wn + j][l][0]);
        GLDS16(gA[0] + k0, &As[cur ^ 1][2 * w + 0][0][0]);
        GLDS16(gA[1] + k0, &As[cur ^ 1][2 * w + 1][0][0]);
        GLDS16(gB + k0,    &Bs[cur ^ 1][w][0][0]);
#pragma unroll
        for (int i = 0; i < 4; i++)
#pragma unroll
            for (int j = 0; j < 2; j++)
                acc[i][j] = __builtin_amdgcn_mfma_f32_16x16x32_bf16(
                    af[i], bfr[j], acc[i][j], 0, 0, 0);
        __syncthreads();
        cur ^= 1;
    }
    {
        v8bf af[4], bfr[2];
#pragma unroll
        for (int i = 0; i < 4; i++) af[i]  = *(const v8bf*)(&As[cur][4 * wm + i][l][0]);
#pragma unroll
        for (int j = 0; j < 2; j++) bfr[j] = *(const v8bf*)(&Bs[cur][2 * wn + j][l][0]);
#pragma unroll
        for (int i = 0; i < 4; i++)
#pragma unroll
            for (int j = 0; j < 2; j++)
                acc[i][j] = __builtin_amdgcn_mfma_f32_16x16x32_bf16(
                    af[i], bfr[j], acc[i][j], 0, 0, 0);
    }

    float bv[2];
#pragma unroll
    for (int j = 0; j < 2; j++) bv[j] = bias[n0 + 32 * wn + 16 * j + r16];
    const int colbase = n0 + 32 * wn + r16;
#pragma unroll
    for (int i = 0; i < 4; i++) {
        int rowb = m0 + 64 * wm + 16 * i + qb * 4;
#pragma unroll
        for (int j = 0; j < 2; j++) {
            int col = colbase + 16 * j;
#pragma unroll
            for (int r = 0; r < 4; r++) {
                int row = rowb + r;
                if (row >= M) continue;
                long long off = (long long)row * ldC + col;
                float vv = acc[i][j][r] + bv[j];
                if (res)  vv += res[off];
                if (relu) vv = fmaxf(vv, 0.f);
                if (Cf) Cf[off] = vv;
                if (Cb) ((unsigned short*)Cb)[off] = f2bfu(vv);
            }
        }
    }
}

// ---------------------------------------------------------------------------
// MFMA softsign attention, K/V DOUBLE-BUFFERED with prefetch-before-compute
// (R10, confirmed gain). Output written in SWIZZLED layout (K=1024 -> 32).
// LDS (us): P/out [0,9216) overlays the dead Q region after the prologue;
// KV buf0 [9216,17408), KV buf1 [17408,25600); K at base, V at base+4096.
// ---------------------------------------------------------------------------
__global__ __launch_bounds__(256) void attn_mfma_k(
    const unsigned short* __restrict__ QKV,
    const unsigned short* __restrict__ Vt,
    unsigned short* __restrict__ Osw)
{
    __shared__ __align__(16) unsigned short lds[25600];
    const int t = threadIdx.x, w = t >> 6, l = t & 63;
    const int bh = blockIdx.y, b = bh >> 4, h = bh & 15;
    const int s0 = blockIdx.x << 7;
    const int r16 = l & 15, q4 = l >> 4;
    const long long qrow0 = (long long)(b << 10) + s0;
    const int hoff = h << 6;

#define LOAD_KV(T0, KVW) do {                                               \
    _Pragma("unroll")                                                       \
    for (int rr_ = 0; rr_ < 2; rr_++) {                                     \
        int r_ = 2 * w + rr_, kk_ = r_ >> 2, j_ = r_ & 3;                   \
        const unsigned short* gk_ = QKV                                     \
            + ((long long)(b << 10) + (T0) + 16 * j_ + r16) * 3072          \
            + 1024 + hoff + 32 * kk_ + q4 * 8;                              \
        GLDS16(gk_, &lds[(KVW) + r_ * 512]);                                \
        const unsigned short* gv_ = Vt + ((long long)b << 20)               \
            + (long long)(hoff + 16 * j_ + r16) * 1024 + (T0)               \
            + 32 * kk_ + q4 * 8;                                            \
        GLDS16(gv_, &lds[(KVW) + 4096 + r_ * 512]);                         \
    }                                                                       \
} while (0)

    // prologue: Q -> [0,8192) and first K/V tile -> buf0
#pragma unroll
    for (int mi = 0; mi < 2; mi++)
#pragma unroll
        for (int kk = 0; kk < 2; kk++) {
            const unsigned short* g = QKV + (qrow0 + 32 * w + 16 * mi + r16) * 3072
                                      + hoff + 32 * kk + q4 * 8;
            GLDS16(g, &lds[(w * 4 + mi * 2 + kk) * 512]);
        }
    LOAD_KV(0, 9216);
    __syncthreads();
    v8bf qf[2][2];
#pragma unroll
    for (int mi = 0; mi < 2; mi++)
#pragma unroll
        for (int kk = 0; kk < 2; kk++)
            qf[mi][kk] = *(const v8bf*)&lds[(w * 4 + mi * 2 + kk) * 512 + l * 8];
    __syncthreads();   // all qf in regs before P overwrites the Q region

    v4f oacc[2][4];
#pragma unroll
    for (int i = 0; i < 2; i++)
#pragma unroll
        for (int j = 0; j < 4; j++) oacc[i][j] = (v4f){0.f, 0.f, 0.f, 0.f};

    int cur = 0;
    for (int it = 0; it < 16; ++it) {
        const int kvr = 9216 + cur * 8192;
        if (it < 15) LOAD_KV((it + 1) * 64, 9216 + (cur ^ 1) * 8192);

        v8bf kf[2][4];
#pragma unroll
        for (int kk = 0; kk < 2; kk++)
#pragma unroll
            for (int j = 0; j < 4; j++)
                kf[kk][j] = *(const v8bf*)&lds[kvr + (kk * 4 + j) * 512 + l * 8];
        v4f sc[2][4];
#pragma unroll
        for (int i = 0; i < 2; i++)
#pragma unroll
            for (int j = 0; j < 4; j++) sc[i][j] = (v4f){0.f, 0.f, 0.f, 0.f};
#pragma unroll
        for (int kk = 0; kk < 2; kk++)
#pragma unroll
            for (int mi = 0; mi < 2; mi++)
#pragma unroll
                for (int j = 0; j < 4; j++)
                    sc[mi][j] = __builtin_amdgcn_mfma_f32_16x16x32_bf16(
                        qf[mi][kk], kf[kk][j], sc[mi][j], 0, 0, 0);

#pragma unroll
        for (int mi = 0; mi < 2; mi++)
#pragma unroll
            for (int j = 0; j < 4; j++)
#pragma unroll
                for (int r = 0; r < 4; r++) {
                    float v = sc[mi][j][r] * 0.125f;
                    float p = v * __builtin_amdgcn_rcpf(1.0f + fabsf(v));
                    lds[(32 * w + 16 * mi + q4 * 4 + r) * 72 + 16 * j + r16] = f2bfu(p);
                }

        v8bf pf[2][2], vf[2][4];
#pragma unroll
        for (int mi = 0; mi < 2; mi++)
#pragma unroll
            for (int kk = 0; kk < 2; kk++)
                pf[mi][kk] = *(const v8bf*)&lds[(32 * w + 16 * mi + r16) * 72
                                                + 32 * kk + q4 * 8];
#pragma unroll
        for (int kk = 0; kk < 2; kk++)
#pragma unroll
            for (int j = 0; j < 4; j++)
                vf[kk][j] = *(const v8bf*)&lds[kvr + 4096 + (kk * 4 + j) * 512 + l * 8];
#pragma unroll
        for (int kk = 0; kk < 2; kk++)
#pragma unroll
            for (int mi = 0; mi < 2; mi++)
#pragma unroll
                for (int j = 0; j < 4; j++)
                    oacc[mi][j] = __builtin_amdgcn_mfma_f32_16x16x32_bf16(
                        pf[mi][kk], vf[kk][j], oacc[mi][j], 0, 0, 0);
        __syncthreads();
        cur ^= 1;
    }
#undef LOAD_KV

#pragma unroll
    for (int mi = 0; mi < 2; mi++)
#pragma unroll
        for (int j = 0; j < 4; j++)
#pragma unroll
            for (int r = 0; r < 4; r++)
                lds[(32 * w + 16 * mi + q4 * 4 + r) * 72 + 16 * j + r16] =
                    f2bfu(oacc[mi][j][r]);
    __syncthreads();
    {
        int row = t >> 1, ch = (t & 1) << 5;
        int grow = (int)qrow0 + row;
#pragma unroll
        for (int i = 0; i < 4; i++) {
            int c0 = hoff + ch + 8 * i;
            v8us vv = *(const v8us*)&lds[row * 72 + ch + 8 * i];
            *(v8us*)(Osw + swidx(grow, c0, 32)) = vv;
        }
    }
}

// ---------------------------------------------------------------------------
// LayerNorm (torch-style), output bf16 in SWIZZLED layout (K=1024).
// ---------------------------------------------------------------------------
__global__ __launch_bounds__(256) void layernorm_k(
    const float* __restrict__ x, const float* __restrict__ w,
    const float* __restrict__ b, unsigned short* __restrict__ ysw)
{
    int row = blockIdx.x;
    int t = threadIdx.x;
    float4 v = ((const float4*)(x + ((long long)row << 10)))[t];
    float s = v.x + v.y + v.z + v.w;
#pragma unroll
    for (int o = 32; o; o >>= 1) s += __shfl_down(s, o);
    __shared__ float red[4];
    __shared__ float red2[4];
    int wid = t >> 6, lane = t & 63;
    if (lane == 0) red[wid] = s;
    __syncthreads();
    float mean = (red[0] + red[1] + red[2] + red[3]) * (1.0f / 1024.0f);
    float dx = v.x - mean, dy = v.y - mean, dz = v.z - mean, dw = v.w - mean;
    float sq = dx * dx + dy * dy + dz * dz + dw * dw;
#pragma unroll
    for (int o = 32; o; o >>= 1) sq += __shfl_down(sq, o);
    if (lane == 0) red2[wid] = sq;
    __syncthreads();
    float var = (red2[0] + red2[1] + red2[2] + red2[3]) * (1.0f / 1023.0f);
    float inv = 1.0f / (sqrtf(var) + 1e-6f);
    float4 W  = ((const float4*)w)[t];
    float4 Bv = ((const float4*)b)[t];
    ushort4 o;
    o.x = f2bfu(W.x * (dx * inv) + Bv.x);
    o.y = f2bfu(W.y * (dy * inv) + Bv.y);
    o.z = f2bfu(W.z * (dz * inv) + Bv.z);
    o.w = f2bfu(W.w * (dw * inv) + Bv.w);
    int c0 = t << 2;
    *(ushort4*)(ysw + swidx(row, c0, 32)) = o;
}

// ---------------------------------------------------------------------------
__global__ __launch_bounds__(256) void add_pos_k(float* __restrict__ h)
{
    int idx = blockIdx.x * 256 + threadIdx.x;
    int d = idx & 1023;
    int s = (idx >> 10) & 1023;
    int e = d & ~1;
    float div = expf(-9.210340371976184f * (float)e * (1.0f / 1024.0f));
    float arg = (float)s * div;
    float pe = (d & 1) ? cosf(arg) : sinf(arg);
    h[idx] += pe;
}

__global__ __launch_bounds__(256) void convert_k(
    const float* __restrict__ src, unsigned short* __restrict__ dst, int n4)
{
    int i = blockIdx.x * 256 + threadIdx.x;
    if (i >= n4) return;
    float4 v = ((const float4*)src)[i];
    ushort4 o;
    o.x = f2bfu(v.x); o.y = f2bfu(v.y); o.z = f2bfu(v.z); o.w = f2bfu(v.w);
    ((ushort4*)dst)[i] = o;
}

// conv2's im2col A (row r: 1536 contiguous bf16 at h1b[(b*1026+s)*512])
// -> fragment-swizzled [4096][1536] (kt=48). 8 us per thread, both sides
// contiguous (swidx is contiguous in k&7 for 8-aligned k).
__global__ __launch_bounds__(256) void convert_h1_sw_k(
    const unsigned short* __restrict__ h1, unsigned short* __restrict__ dst)
{
    int g = blockIdx.x * 256 + threadIdx.x;   // [0, 786432)
    int r  = g / 192;                          // 1536/8 chunks per row
    int k8 = (g - r * 192) * 8;
    int b = r >> 10, s = r & 1023;
    v8us v = *(const v8us*)(h1 + (((long long)(b * 1026 + s)) << 9) + k8);
    *(v8us*)(dst + swidx(r, k8, 48)) = v;
}

// conv weights [OC][IC][3] fp32 -> bf16 fragment-swizzled [OC][3*IC] (K-col
// = tap*IC + ic, matching the contiguous im2col A layout).
__global__ __launch_bounds__(256) void reorder_w_sw_k(
    const float* __restrict__ src, unsigned short* __restrict__ dst,
    int OC, int IC, int kt)
{
    int idx = blockIdx.x * 256 + threadIdx.x;
    if (idx >= OC * IC * 3) return;
    int k  = idx % 3;
    int ic = (idx / 3) % IC;
    int oc = idx / (3 * IC);
    dst[swidx(oc, k * IC + ic, kt)] = f2bfu(src[idx]);
}

// Layer weights fp32 row-major -> bf16 SWIZZLED, all 6 matrices, one launch.
// dst layout (us): q,k,v,o (1M each), f1 (2M), f2 (2M) — contiguous.
__global__ __launch_bounds__(256) void convert_layer_sw_k(
    const float* __restrict__ q, const float* __restrict__ k,
    const float* __restrict__ v, const float* __restrict__ o,
    const float* __restrict__ f1, const float* __restrict__ f2,
    unsigned short* __restrict__ dst)
{
    int idx = blockIdx.x * 256 + threadIdx.x;   // float4 index, [0, 2M)
    const float* src;
    unsigned short* db;
    int Ksh, rf;
    if (idx < 0x100000) {
        int region = idx >> 18;
        rf = idx & 0x3FFFF;
        src = (region == 0) ? q : (region == 1) ? k : (region == 2) ? v : o;
        db = dst + ((long long)region << 20);
        Ksh = 10;
    } else if (idx < 0x180000) {
        rf = idx - 0x100000; src = f1; db = dst + (4LL << 20); Ksh = 10;
    } else {
        rf = idx - 0x180000; src = f2; db = dst + (6LL << 20); Ksh = 11;
    }
    float4 vv = ((const float4*)src)[rf];
    int flatf = rf << 2;
    int n  = flatf >> Ksh;
    int k0 = flatf & ((1 << Ksh) - 1);
    ushort4 ov;
    ov.x = f2bfu(vv.x); ov.y = f2bfu(vv.y); ov.z = f2bfu(vv.z); ov.w = f2bfu(vv.w);
    *(ushort4*)(db + swidx(n, k0, 1 << (Ksh - 5))) = ov;
}

__global__ __launch_bounds__(256) void concat3_k(
    const float* __restrict__ a, const float* __restrict__ b,
    const float* __restrict__ c, float* __restrict__ o)
{
    int i = blockIdx.x * 256 + threadIdx.x;
    o[i] = (i < 1024) ? a[i] : ((i < 2048) ? b[i - 1024] : c[i - 2048]);
}

__global__ __launch_bounds__(256) void reorder_w_k(
    const float* __restrict__ src, unsigned short* __restrict__ dst, int OC, int IC)
{
    int idx = blockIdx.x * 256 + threadIdx.x;
    if (idx >= OC * IC * 3) return;
    int k  = idx % 3;
    int ic = (idx / 3) % IC;
    int oc = idx / (3 * IC);
    dst[(oc * 3 + k) * IC + ic] = f2bfu(src[idx]);
}

// meanpool split: 256-block partial pass (16 rows each, all 1024 d) then a
// 16-block reduce. Old single-pass version ran on only 16 CUs pulling 16 MB.
__global__ __launch_bounds__(256) void meanpool_part_k(
    const float* __restrict__ h, float* __restrict__ part)
{
    int g = blockIdx.x;                 // g = b*64 + rblk
    int b = g >> 6, rblk = g & 63;
    const float4* base = (const float4*)(h + ((long long)b << 20)
                                           + ((long long)(rblk * 16) << 10));
    float4 s = {0.f, 0.f, 0.f, 0.f};
#pragma unroll
    for (int i = 0; i < 16; i++) {
        float4 v = base[i * 256 + threadIdx.x];
        s.x += v.x; s.y += v.y; s.z += v.z; s.w += v.w;
    }
    ((float4*)part)[g * 256 + threadIdx.x] = s;
}

__global__ __launch_bounds__(256) void meanpool_red_k(
    const float* __restrict__ part, float* __restrict__ pooled)
{
    int idx = blockIdx.x * 256 + threadIdx.x;   // 4096: b = idx>>10, d = idx&1023
    int b = idx >> 10, d = idx & 1023;
    const float* p = part + ((long long)(b * 64) << 10) + d;
    float s = 0.f;
#pragma unroll 8
    for (int r = 0; r < 64; r++) s += p[r << 10];
    pooled[idx] = s * (1.0f / 1024.0f);
}

__global__ __launch_bounds__(256) void fc_k(
    const float* __restrict__ p, const float* __restrict__ w,
    const float* __restrict__ fb, float* __restrict__ out)
{
    int b = blockIdx.x, t = threadIdx.x;
    float s = 0.f;
    for (int i = t; i < 1024; i += 256) s += p[(b << 10) + i] * w[i];
#pragma unroll
    for (int o = 32; o; o >>= 1) s += __shfl_down(s, o);
    __shared__ float red[4];
    if ((t & 63) == 0) red[t >> 6] = s;
    __syncthreads();
    if (t == 0) out[b] = red[0] + red[1] + red[2] + red[3] + fb[0];
}

// ---------------------------------------------------------------------------
extern "C" void kernel_launch(void* const* d_in, const int* in_sizes, int n_in,
                              void* d_out, int out_size, void* d_ws, size_t ws_size,
                              hipStream_t stream)
{
    const float* x    = (const float*)d_in[0];
    const float* c1w  = (const float*)d_in[1];
    const float* c1b  = (const float*)d_in[2];
    const float* c2w  = (const float*)d_in[3];
    const float* c2b  = (const float*)d_in[4];
    const float* lnAw = (const float*)d_in[5];
    const float* lnAb = (const float*)d_in[6];
    const float* qw   = (const float*)d_in[7];
    const float* qbi  = (const float*)d_in[8];
    const float* kw   = (const float*)d_in[9];
    const float* kbi  = (const float*)d_in[10];
    const float* vw   = (const float*)d_in[11];
    const float* vbi  = (const float*)d_in[12];
    const float* ow   = (const float*)d_in[13];
    const float* obi  = (const float*)d_in[14];
    const float* lnBw = (const float*)d_in[15];
    const float* lnBb = (const float*)d_in[16];
    const float* f1w  = (const float*)d_in[17];
    const float* f1b  = (const float*)d_in[18];
    const float* f2w  = (const float*)d_in[19];
    const float* f2b  = (const float*)d_in[20];
    const float* fcw  = (const float*)d_in[21];
    const float* fcb  = (const float*)d_in[22];
    float* out = (float*)d_out;

    float* ws = (float*)d_ws;
    typedef __hip_bfloat16 bf;
    typedef unsigned short us;
    float* h    = ws;                          // 4,194,304 f
    us* hn_b    = (us*)(ws + 4194304);         // 4M us (swizzled activations)
    us* qkv_b   = (us*)(ws + 6291456);         // [4096][3072] us row-major
    us* ff_b    = qkv_b;                       // [4096][2048] swizzled overlay
    us* h1sw    = qkv_b;                       // conv2 A swizzled (pre-loop)
    us* wq_b    = (us*)(ws + 12582912);        // swizzled: q,k,v,o,f1,f2
    us* wo_b    = (us*)(ws + 14155776);
    us* wf1_b   = (us*)(ws + 14680064);
    us* wf2_b   = (us*)(ws + 15728640);
    us* xb      = (us*)(ws + 16777216);
    us* h1b     = (us*)(ws + 16912896);
    us* w1t_b   = (us*)(ws + 17963520);
    us* w2t_b   = (us*)(ws + 18012672);        // conv2 W swizzled (kt=48)
    float* pooled = ws + 18799104;             // 4,096 f
    us* Vt      = (us*)(ws + 18803200);        // [4][1024 d][1024 t] us
    float* bqkv = ws + 20900352;               // 3,072 f
    float* mp_part = ws + 20903424;            // 262,144 f (meanpool partials)

    convert_k<<<dim3(257), 256, 0, stream>>>(x, xb, 65792);
    reorder_w_k<<<dim3(384),  256, 0, stream>>>(c1w, w1t_b, 512, 64);
    reorder_w_sw_k<<<dim3(6144), 256, 0, stream>>>(c2w, w2t_b, 1024, 512, 48);

    // conv1: M=4104, N=512, K=192 (LDS-staged kernel, row-remapped A)
    gemm_mfma_k<<<dim3(8, 33), 256, 0, stream>>>(
        (const bf*)xb, 1026, 1028LL * 64, 64, (const bf*)w1t_b,
        c1b, nullptr, nullptr, (bf*)h1b, 4104, 512, 192, 512, 0);
    // conv2 A: im2col rows are contiguous in h1b -> swizzle copy (kt=48)
    convert_h1_sw_k<<<dim3(3072), 256, 0, stream>>>(h1b, h1sw);
    // conv2: M=4096, N=1024, K=1536 on the fast swizzled GEMM
    gemm_sw_k<<<dim3(16, 64), 64, 0, stream>>>(
        h1sw, w2t_b, c2b, nullptr, h, nullptr, nullptr, nullptr, 0,
        4096, 1024, 1536, 1024, 0);
    add_pos_k<<<dim3(16384), 256, 0, stream>>>(h);

    for (int l = 0; l < 4; l++) {
        long long wo  = (long long)l * 1048576;
        long long wo2 = (long long)l * 2097152;
        convert_layer_sw_k<<<dim3(8192), 256, 0, stream>>>(
            qw + wo, kw + wo, vw + wo, ow + wo, f1w + wo2, f2w + wo2, wq_b);
        concat3_k<<<dim3(12), 256, 0, stream>>>(qbi + l * 1024, kbi + l * 1024,
                                                vbi + l * 1024, bqkv);

        layernorm_k<<<dim3(4096), 256, 0, stream>>>(h, lnAw + l * 1024, lnAb + l * 1024, hn_b);
        // fused QKV: N=3072; Q,K swizzled to qkv_b; V transposed to Vt
        gemm_sw_k<<<dim3(48, 64), 64, 0, stream>>>(
            hn_b, wq_b, bqkv, nullptr, nullptr, qkv_b, nullptr, Vt, 2048,
            4096, 3072, 1024, 3072, 0);
        attn_mfma_k<<<dim3(8, 64), 256, 0, stream>>>(qkv_b, Vt, hn_b);
        // O-proj: out fp32 h += res
        gemm_sw_k<<<dim3(16, 64), 64, 0, stream>>>(
            hn_b, wo_b, obi + l * 1024, h, h, nullptr, nullptr, nullptr, 0,
            4096, 1024, 1024, 1024, 0);
        layernorm_k<<<dim3(4096), 256, 0, stream>>>(h, lnBw + l * 1024, lnBb + l * 1024, hn_b);
        // FF1: out swizzled bf16 (+relu)
        gemm_sw_k<<<dim3(32, 64), 64, 0, stream>>>(
            hn_b, wf1_b, f1b + l * 2048, nullptr, nullptr, nullptr, ff_b, nullptr, 0,
            4096, 2048, 1024, 2048, 1);
        // FF2: out fp32 h += res
        gemm_sw_k<<<dim3(16, 64), 64, 0, stream>>>(
            ff_b, wf2_b, f2b + l * 1024, h, h, nullptr, nullptr, nullptr, 0,
            4096, 1024, 2048, 1024, 0);
    }

    meanpool_part_k<<<dim3(256), 256, 0, stream>>>(h, mp_part);
    meanpool_red_k<<<dim3(16), 256, 0, stream>>>(mp_part, pooled);
    fc_k<<<dim3(4), 256, 0, stream>>>(pooled, fcw, fcb, out);
}

// Round 12
// 1086.683 us; speedup vs baseline: 1.5125x; 1.0030x over previous
//
#include <hip/hip_runtime.h>
#include <hip/hip_bf16.h>
#include <math.h>

// ---------------------------------------------------------------------------
// helpers
// ---------------------------------------------------------------------------
typedef __bf16 v8bf __attribute__((ext_vector_type(8)));
typedef float  v4f  __attribute__((ext_vector_type(4)));
typedef unsigned short v8us __attribute__((ext_vector_type(8)));

__device__ __forceinline__ unsigned short f2bfu(float f) {
    unsigned u = __builtin_bit_cast(unsigned, f);
    unsigned r = (u + 0x7fffu + ((u >> 16) & 1u)) >> 16;
    return (unsigned short)r;
}
__device__ __forceinline__ float bf2f(unsigned short u) {
    unsigned x = ((unsigned)u) << 16;
    return __builtin_bit_cast(float, x);
}

// fragment-swizzled element address: matrix [rows][K cols] stored so that a
// wave's 16x32 MFMA fragment is contiguous: sw(r,k) =
//   tile(r>>4, k>>5) * 512 + lane((k>>3)&3, r&15) * 8 + (k&7)
__device__ __forceinline__ long long swidx(int r, int k, int kt /*=K>>5*/) {
    return ((long long)((r >> 4) * kt + (k >> 5)) << 9)
         + (((k >> 3) & 3) << 7) + ((r & 15) << 3) + (k & 7);
}

#define GLDS16(g, s)                                                        \
    __builtin_amdgcn_global_load_lds(                                       \
        (const __attribute__((address_space(1))) void*)(g),                 \
        (__attribute__((address_space(3))) void*)(s), 16, 0, 0)

// ---------------------------------------------------------------------------
// SWIZZLED register-direct bf16 MFMA GEMM (no LDS, no barriers).
// A (M x K) and B (N x K) in fragment-swizzled layout (see swidx).
// ONE WAVE PER BLOCK (64 threads), wave tile 64x64; R4 branch-free ring
// body (compiler collapses it; accepted — R1-R10 exhausted schedule levers;
// kernel sits at the L2-miss-traffic + exposed-latency floor).
//
// Block mapping (R9, verified: QKV FETCH 72->35MB): 8 L2-sized regions
// (4 by-strips x 2 bx-strips) selected by bid&7; 4x4 micro-tiles inside,
// micro-rows major. Guard: nbx%8==0 && nby%16==0 (all grids qualify).
//
// resmod=1: res is a [1024][ldC] table indexed by (row&1023) — used to
// fuse the positional-encoding add into conv2's epilogue.
//
// Outputs: Cf (fp32,+res row-major) | Cb (bf16 row-major) | Csw (bf16
// swizzled for the next GEMM, K_consumer = N) ; cols >= ctcol0 (Ct!=null)
// go transposed to Ct (attention V^T). M,N multiples of 64, kt=K/32
// a multiple of 4 and >= 8 (kt = 32, 48 or 64 here).
// ---------------------------------------------------------------------------
#define LOAD_CHUNK(R, C) do {                                               \
    const long long o_ = (long long)(C) << 9;                               \
    _Pragma("unroll")                                                       \
    for (int i_ = 0; i_ < 4; i_++) Ab[R][i_] = *(const v8bf*)(pa[i_] + o_); \
    _Pragma("unroll")                                                       \
    for (int j_ = 0; j_ < 4; j_++) Bb[R][j_] = *(const v8bf*)(pb[j_] + o_); \
} while (0)

#define MFMA_CHUNK(R) do {                                                  \
    _Pragma("unroll")                                                       \
    for (int i_ = 0; i_ < 4; i_++)                                          \
    _Pragma("unroll")                                                       \
    for (int j_ = 0; j_ < 4; j_++)                                          \
        acc[i_][j_] = __builtin_amdgcn_mfma_f32_16x16x32_bf16(              \
            Ab[R][i_], Bb[R][j_], acc[i_][j_], 0, 0, 0);                    \
} while (0)

__global__ __launch_bounds__(64, 2) void gemm_sw_k(
    const unsigned short* __restrict__ Asw,
    const unsigned short* __restrict__ Bsw,
    const float* __restrict__ bias,
    const float* __restrict__ res,
    float* __restrict__ Cf,
    unsigned short* __restrict__ Cb,
    unsigned short* __restrict__ Csw,
    unsigned short* __restrict__ Ct, int ctcol0,
    int M, int N, int K, int ldC, int relu, int resmod)
{
    const int l = threadIdx.x;

    int bx = blockIdx.x, by = blockIdx.y;
    {
        int nbx = gridDim.x, nby = gridDim.y;
        if (((nbx & 7) == 0) && ((nby & 15) == 0)) {
            // L2-locality mapping: 8 XCD regions (4 by-strips x 2 bx-strips),
            // 4x4 micro-tiles inside, micro-rows major. Bijective.
            int bid   = by * nbx + bx;
            int xcd   = bid & 7;
            int local = bid >> 3;             // [0, nb/8)
            int rby = nby >> 2;               // region height (blocks)
            int rbx = nbx >> 1;               // region width
            int u   = local & 15;             // 4x4 micro-tile cell
            int mt  = local >> 4;             // micro-tile index
            int mtxc = rbx >> 2;              // micro-tiles per region row
            int mty = mt / mtxc;
            int mtx = mt - mty * mtxc;
            by = (xcd >> 1) * rby + (mty << 2) + (u >> 2);
            bx = (xcd & 1) * rbx + (mtx << 2) + (u & 3);
        } else {
            int nb = nbx * nby;
            if ((nb & 7) == 0) {              // fallback: old XCD swizzle
                int bid = by * nbx + bx;
                int nid = (bid & 7) * (nb >> 3) + (bid >> 3);
                by = nid / nbx;
                bx = nid - by * nbx;
            }
        }
    }
    const int m0 = by * 64;
    const int n0 = bx * 64;
    const int r16 = l & 15;
    const int qb  = l >> 4;
    const int kt = K >> 5;

    // fragment base pointers: contiguous 16B per lane
    const unsigned short* pa[4];
#pragma unroll
    for (int i = 0; i < 4; i++)
        pa[i] = Asw + ((long long)(((m0 >> 4) + i) * kt) << 9) + l * 8;
    const unsigned short* pb[4];
#pragma unroll
    for (int j = 0; j < 4; j++)
        pb[j] = Bsw + ((long long)(((n0 >> 4) + j) * kt) << 9) + l * 8;

    v4f acc[4][4];
#pragma unroll
    for (int i = 0; i < 4; i++)
#pragma unroll
        for (int j = 0; j < 4; j++) acc[i][j] = (v4f){0.f, 0.f, 0.f, 0.f};

    v8bf Ab[4][4], Bb[4][4];

    // prologue: chunks 0,1,2 -> rings 0,1,2
    LOAD_CHUNK(0, 0);
    LOAD_CHUNK(1, 1);
    LOAD_CHUNK(2, 2);

    // steady state: straight-line, no branches, literal ring indices.
    int s = 0;
    for (; s < kt - 4; s += 4) {
        LOAD_CHUNK(3, s + 3); MFMA_CHUNK(0);
        LOAD_CHUNK(0, s + 4); MFMA_CHUNK(1);
        LOAD_CHUNK(1, s + 5); MFMA_CHUNK(2);
        LOAD_CHUNK(2, s + 6); MFMA_CHUNK(3);
    }
    // epilogue: s == kt-4; rings hold kt-4,kt-3,kt-2; load last chunk.
    LOAD_CHUNK(3, kt - 1);
    MFMA_CHUNK(0); MFMA_CHUNK(1); MFMA_CHUNK(2); MFMA_CHUNK(3);

    float bv[4];
#pragma unroll
    for (int j = 0; j < 4; j++) bv[j] = bias[n0 + 16 * j + r16];
    const int colbase = n0 + r16;
    const int nt = N >> 5;
#pragma unroll
    for (int i = 0; i < 4; i++) {
        int rowb = m0 + 16 * i + qb * 4;
#pragma unroll
        for (int j = 0; j < 4; j++) {
            int col = colbase + 16 * j;
            float v[4];
#pragma unroll
            for (int r = 0; r < 4; r++) v[r] = acc[i][j][r] + bv[j];
            if (Ct && col >= ctcol0) {
                ushort4 o;
                o.x = f2bfu(v[0]); o.y = f2bfu(v[1]);
                o.z = f2bfu(v[2]); o.w = f2bfu(v[3]);
                *(ushort4*)(Ct + ((long long)(rowb >> 10) << 20)
                            + (long long)(col - ctcol0) * 1024 + (rowb & 1023)) = o;
            } else if (Csw) {
#pragma unroll
                for (int r = 0; r < 4; r++) {
                    int row = rowb + r;
                    float vv = v[r];
                    if (relu) vv = fmaxf(vv, 0.f);
                    Csw[swidx(row, col, nt)] = f2bfu(vv);
                }
            } else {
#pragma unroll
                for (int r = 0; r < 4; r++) {
                    int row = rowb + r;
                    long long off = (long long)row * ldC + col;
                    float vv = v[r];
                    if (res) {
                        long long roff = resmod
                            ? ((long long)(row & 1023) * ldC + col) : off;
                        vv += res[roff];
                    }
                    if (relu) vv = fmaxf(vv, 0.f);
                    if (Cf) Cf[off] = vv;
                    if (Cb) ((unsigned short*)Cb)[off] = f2bfu(vv);
                }
            }
        }
    }
}

// ---------------------------------------------------------------------------
// LDS-staged GEMM — kept ONLY for conv1 (M=4104 not a multiple of 64).
// ---------------------------------------------------------------------------
__global__ __launch_bounds__(256) void gemm_mfma_k(
    const __hip_bfloat16* __restrict__ A, int rpbA, long long bstrideA, int ldA,
    const __hip_bfloat16* __restrict__ B,
    const float* __restrict__ bias,
    const float* __restrict__ res,
    float* __restrict__ Cf,
    __hip_bfloat16* __restrict__ Cb,
    int M, int N, int K, int ldC, int relu)
{
    __shared__ __align__(16) __hip_bfloat16 As[2][8][64][8];
    __shared__ __align__(16) __hip_bfloat16 Bs[2][4][64][8];
    const int t  = threadIdx.x;
    const int w  = t >> 6;
    const int l  = t & 63;
    const int m0 = blockIdx.y * 128;
    const int n0 = blockIdx.x * 64;
    const int r16 = l & 15;
    const int qb  = l >> 4;
    const int wm = w >> 1, wn = w & 1;

    const __hip_bfloat16* gA[2];
#pragma unroll
    for (int tt = 0; tt < 2; tt++) {
        int arow = m0 + 16 * (2 * w + tt) + r16;
        gA[tt] = A + (long long)(arow / rpbA) * bstrideA
                   + (long long)(arow % rpbA) * ldA + qb * 8;
    }
    const __hip_bfloat16* gB = B + (long long)(n0 + 16 * w + r16) * K + qb * 8;

    v4f acc[4][2];
#pragma unroll
    for (int i = 0; i < 4; i++)
#pragma unroll
        for (int j = 0; j < 2; j++) acc[i][j] = (v4f){0.f, 0.f, 0.f, 0.f};

    GLDS16(gA[0], &As[0][2 * w + 0][0][0]);
    GLDS16(gA[1], &As[0][2 * w + 1][0][0]);
    GLDS16(gB,    &Bs[0][w][0][0]);
    __syncthreads();

    int cur = 0;
    for (int k0 = 32; k0 < K; k0 += 32) {
        v8bf af[4], bfr[2];
#pragma unroll
        for (int i = 0; i < 4; i++) af[i]  = *(const v8bf*)(&As[cur][4 * wm + i][l][0]);
#pragma unroll
        for (int j = 0; j < 2; j++) bfr[j] = *(const v8bf*)(&Bs[cur][2 * wn + j][l][0]);
        GLDS16(gA[0] + k0, &As[cur ^ 1][2 * w + 0][0][0]);
        GLDS16(gA[1] + k0, &As[cur ^ 1][2 * w + 1][0][0]);
        GLDS16(gB + k0,    &Bs[cur ^ 1][w][0][0]);
#pragma unroll
        for (int i = 0; i < 4; i++)
#pragma unroll
            for (int j = 0; j < 2; j++)
                acc[i][j] = __builtin_amdgcn_mfma_f32_16x16x32_bf16(
                    af[i], bfr[j], acc[i][j], 0, 0, 0);
        __syncthreads();
        cur ^= 1;
    }
    {
        v8bf af[4], bfr[2];
#pragma unroll
        for (int i = 0; i < 4; i++) af[i]  = *(const v8bf*)(&As[cur][4 * wm + i][l][0]);
#pragma unroll
        for (int j = 0; j < 2; j++) bfr[j] = *(const v8bf*)(&Bs[cur][2 * wn + j][l][0]);
#pragma unroll
        for (int i = 0; i < 4; i++)
#pragma unroll
            for (int j = 0; j < 2; j++)
                acc[i][j] = __builtin_amdgcn_mfma_f32_16x16x32_bf16(
                    af[i], bfr[j], acc[i][j], 0, 0, 0);
    }

    float bv[2];
#pragma unroll
    for (int j = 0; j < 2; j++) bv[j] = bias[n0 + 32 * wn + 16 * j + r16];
    const int colbase = n0 + 32 * wn + r16;
#pragma unroll
    for (int i = 0; i < 4; i++) {
        int rowb = m0 + 64 * wm + 16 * i + qb * 4;
#pragma unroll
        for (int j = 0; j < 2; j++) {
            int col = colbase + 16 * j;
#pragma unroll
            for (int r = 0; r < 4; r++) {
                int row = rowb + r;
                if (row >= M) continue;
                long long off = (long long)row * ldC + col;
                float vv = acc[i][j][r] + bv[j];
                if (res)  vv += res[off];
                if (relu) vv = fmaxf(vv, 0.f);
                if (Cf) Cf[off] = vv;
                if (Cb) ((unsigned short*)Cb)[off] = f2bfu(vv);
            }
        }
    }
}

// ---------------------------------------------------------------------------
// MFMA softsign attention, K/V DOUBLE-BUFFERED with prefetch-before-compute
// (R10, confirmed gain). Q pre-scaled by 1/8 at weight-convert time (exact
// bf16 exponent shift), so no scale here. Output SWIZZLED (K=1024 -> 32).
// LDS (us): P/out [0,9216) overlays the dead Q region after the prologue;
// KV buf0 [9216,17408), KV buf1 [17408,25600); K at base, V at base+4096.
// ---------------------------------------------------------------------------
__global__ __launch_bounds__(256) void attn_mfma_k(
    const unsigned short* __restrict__ QKV,
    const unsigned short* __restrict__ Vt,
    unsigned short* __restrict__ Osw)
{
    __shared__ __align__(16) unsigned short lds[25600];
    const int t = threadIdx.x, w = t >> 6, l = t & 63;
    const int bh = blockIdx.y, b = bh >> 4, h = bh & 15;
    const int s0 = blockIdx.x << 7;
    const int r16 = l & 15, q4 = l >> 4;
    const long long qrow0 = (long long)(b << 10) + s0;
    const int hoff = h << 6;

#define LOAD_KV(T0, KVW) do {                                               \
    _Pragma("unroll")                                                       \
    for (int rr_ = 0; rr_ < 2; rr_++) {                                     \
        int r_ = 2 * w + rr_, kk_ = r_ >> 2, j_ = r_ & 3;                   \
        const unsigned short* gk_ = QKV                                     \
            + ((long long)(b << 10) + (T0) + 16 * j_ + r16) * 3072          \
            + 1024 + hoff + 32 * kk_ + q4 * 8;                              \
        GLDS16(gk_, &lds[(KVW) + r_ * 512]);                                \
        const unsigned short* gv_ = Vt + ((long long)b << 20)               \
            + (long long)(hoff + 16 * j_ + r16) * 1024 + (T0)               \
            + 32 * kk_ + q4 * 8;                                            \
        GLDS16(gv_, &lds[(KVW) + 4096 + r_ * 512]);                         \
    }                                                                       \
} while (0)

    // prologue: Q -> [0,8192) and first K/V tile -> buf0
#pragma unroll
    for (int mi = 0; mi < 2; mi++)
#pragma unroll
        for (int kk = 0; kk < 2; kk++) {
            const unsigned short* g = QKV + (qrow0 + 32 * w + 16 * mi + r16) * 3072
                                      + hoff + 32 * kk + q4 * 8;
            GLDS16(g, &lds[(w * 4 + mi * 2 + kk) * 512]);
        }
    LOAD_KV(0, 9216);
    __syncthreads();
    v8bf qf[2][2];
#pragma unroll
    for (int mi = 0; mi < 2; mi++)
#pragma unroll
        for (int kk = 0; kk < 2; kk++)
            qf[mi][kk] = *(const v8bf*)&lds[(w * 4 + mi * 2 + kk) * 512 + l * 8];
    __syncthreads();   // all qf in regs before P overwrites the Q region

    v4f oacc[2][4];
#pragma unroll
    for (int i = 0; i < 2; i++)
#pragma unroll
        for (int j = 0; j < 4; j++) oacc[i][j] = (v4f){0.f, 0.f, 0.f, 0.f};

    int cur = 0;
    for (int it = 0; it < 16; ++it) {
        const int kvr = 9216 + cur * 8192;
        if (it < 15) LOAD_KV((it + 1) * 64, 9216 + (cur ^ 1) * 8192);

        v8bf kf[2][4];
#pragma unroll
        for (int kk = 0; kk < 2; kk++)
#pragma unroll
            for (int j = 0; j < 4; j++)
                kf[kk][j] = *(const v8bf*)&lds[kvr + (kk * 4 + j) * 512 + l * 8];
        v4f sc[2][4];
#pragma unroll
        for (int i = 0; i < 2; i++)
#pragma unroll
            for (int j = 0; j < 4; j++) sc[i][j] = (v4f){0.f, 0.f, 0.f, 0.f};
#pragma unroll
        for (int kk = 0; kk < 2; kk++)
#pragma unroll
            for (int mi = 0; mi < 2; mi++)
#pragma unroll
                for (int j = 0; j < 4; j++)
                    sc[mi][j] = __builtin_amdgcn_mfma_f32_16x16x32_bf16(
                        qf[mi][kk], kf[kk][j], sc[mi][j], 0, 0, 0);

#pragma unroll
        for (int mi = 0; mi < 2; mi++)
#pragma unroll
            for (int j = 0; j < 4; j++)
#pragma unroll
                for (int r = 0; r < 4; r++) {
                    float v = sc[mi][j][r];
                    float p = v * __builtin_amdgcn_rcpf(1.0f + fabsf(v));
                    lds[(32 * w + 16 * mi + q4 * 4 + r) * 72 + 16 * j + r16] = f2bfu(p);
                }

        v8bf pf[2][2], vf[2][4];
#pragma unroll
        for (int mi = 0; mi < 2; mi++)
#pragma unroll
            for (int kk = 0; kk < 2; kk++)
                pf[mi][kk] = *(const v8bf*)&lds[(32 * w + 16 * mi + r16) * 72
                                                + 32 * kk + q4 * 8];
#pragma unroll
        for (int kk = 0; kk < 2; kk++)
#pragma unroll
            for (int j = 0; j < 4; j++)
                vf[kk][j] = *(const v8bf*)&lds[kvr + 4096 + (kk * 4 + j) * 512 + l * 8];
#pragma unroll
        for (int kk = 0; kk < 2; kk++)
#pragma unroll
            for (int mi = 0; mi < 2; mi++)
#pragma unroll
                for (int j = 0; j < 4; j++)
                    oacc[mi][j] = __builtin_amdgcn_mfma_f32_16x16x32_bf16(
                        pf[mi][kk], vf[kk][j], oacc[mi][j], 0, 0, 0);
        __syncthreads();
        cur ^= 1;
    }
#undef LOAD_KV

#pragma unroll
    for (int mi = 0; mi < 2; mi++)
#pragma unroll
        for (int j = 0; j < 4; j++)
#pragma unroll
            for (int r = 0; r < 4; r++)
                lds[(32 * w + 16 * mi + q4 * 4 + r) * 72 + 16 * j + r16] =
                    f2bfu(oacc[mi][j][r]);
    __syncthreads();
    {
        int row = t >> 1, ch = (t & 1) << 5;
        int grow = (int)qrow0 + row;
#pragma unroll
        for (int i = 0; i < 4; i++) {
            int c0 = hoff + ch + 8 * i;
            v8us vv = *(const v8us*)&lds[row * 72 + ch + 8 * i];
            *(v8us*)(Osw + swidx(grow, c0, 32)) = vv;
        }
    }
}

// ---------------------------------------------------------------------------
// LayerNorm (torch-style), output bf16 in SWIZZLED layout (K=1024).
// ---------------------------------------------------------------------------
__global__ __launch_bounds__(256) void layernorm_k(
    const float* __restrict__ x, const float* __restrict__ w,
    const float* __restrict__ b, unsigned short* __restrict__ ysw)
{
    int row = blockIdx.x;
    int t = threadIdx.x;
    float4 v = ((const float4*)(x + ((long long)row << 10)))[t];
    float s = v.x + v.y + v.z + v.w;
#pragma unroll
    for (int o = 32; o; o >>= 1) s += __shfl_down(s, o);
    __shared__ float red[4];
    __shared__ float red2[4];
    int wid = t >> 6, lane = t & 63;
    if (lane == 0) red[wid] = s;
    __syncthreads();
    float mean = (red[0] + red[1] + red[2] + red[3]) * (1.0f / 1024.0f);
    float dx = v.x - mean, dy = v.y - mean, dz = v.z - mean, dw = v.w - mean;
    float sq = dx * dx + dy * dy + dz * dz + dw * dw;
#pragma unroll
    for (int o = 32; o; o >>= 1) sq += __shfl_down(sq, o);
    if (lane == 0) red2[wid] = sq;
    __syncthreads();
    float var = (red2[0] + red2[1] + red2[2] + red2[3]) * (1.0f / 1023.0f);
    float inv = 1.0f / (sqrtf(var) + 1e-6f);
    float4 W  = ((const float4*)w)[t];
    float4 Bv = ((const float4*)b)[t];
    ushort4 o;
    o.x = f2bfu(W.x * (dx * inv) + Bv.x);
    o.y = f2bfu(W.y * (dy * inv) + Bv.y);
    o.z = f2bfu(W.z * (dz * inv) + Bv.z);
    o.w = f2bfu(W.w * (dw * inv) + Bv.w);
    int c0 = t << 2;
    *(ushort4*)(ysw + swidx(row, c0, 32)) = o;
}

// ---------------------------------------------------------------------------
// positional-encoding table pe[s][d], s,d in [0,1024): written once, fused
// into conv2's epilogue via resmod=1.
__global__ __launch_bounds__(256) void pe_init_k(float* __restrict__ pe)
{
    int idx = blockIdx.x * 256 + threadIdx.x;
    int d = idx & 1023;
    int s = idx >> 10;
    int e = d & ~1;
    float div = expf(-9.210340371976184f * (float)e * (1.0f / 1024.0f));
    float arg = (float)s * div;
    pe[idx] = (d & 1) ? cosf(arg) : sinf(arg);
}

__global__ __launch_bounds__(256) void convert_k(
    const float* __restrict__ src, unsigned short* __restrict__ dst, int n4)
{
    int i = blockIdx.x * 256 + threadIdx.x;
    if (i >= n4) return;
    float4 v = ((const float4*)src)[i];
    ushort4 o;
    o.x = f2bfu(v.x); o.y = f2bfu(v.y); o.z = f2bfu(v.z); o.w = f2bfu(v.w);
    ((ushort4*)dst)[i] = o;
}

// conv2's im2col A (row r: 1536 contiguous bf16 at h1b[(b*1026+s)*512])
// -> fragment-swizzled [4096][1536] (kt=48).
__global__ __launch_bounds__(256) void convert_h1_sw_k(
    const unsigned short* __restrict__ h1, unsigned short* __restrict__ dst)
{
    int g = blockIdx.x * 256 + threadIdx.x;   // [0, 786432)
    int r  = g / 192;                          // 1536/8 chunks per row
    int k8 = (g - r * 192) * 8;
    int b = r >> 10, s = r & 1023;
    v8us v = *(const v8us*)(h1 + (((long long)(b * 1026 + s)) << 9) + k8);
    *(v8us*)(dst + swidx(r, k8, 48)) = v;
}

// both conv weight reorders in ONE launch: blocks [0,384) conv1 (row-major
// [oc][3*64]), blocks [384,6528) conv2 (fragment-swizzled kt=48).
__global__ __launch_bounds__(256) void reorder_all_w_k(
    const float* __restrict__ c1w, const float* __restrict__ c2w,
    unsigned short* __restrict__ w1t, unsigned short* __restrict__ w2t)
{
    if (blockIdx.x < 384) {
        int idx = blockIdx.x * 256 + threadIdx.x;       // < 98304 exact
        int k  = idx % 3;
        int ic = (idx / 3) % 64;
        int oc = idx / 192;
        w1t[(oc * 3 + k) * 64 + ic] = f2bfu(c1w[idx]);
    } else {
        int idx = (blockIdx.x - 384) * 256 + threadIdx.x; // < 1572864 exact
        int k  = idx % 3;
        int ic = (idx / 3) % 512;
        int oc = idx / 1536;
        w2t[swidx(oc, k * 512 + ic, 48)] = f2bfu(c2w[idx]);
    }
}

// Layer weights fp32 row-major -> bf16 SWIZZLED, all 6 matrices, PLUS the
// qkv bias concat (blocks >= 8192), in one launch. Q weights and bias are
// pre-scaled by 1/8 (exact bf16 exponent shift) so attn skips the scale.
// dst layout (us): q,k,v,o (1M each), f1 (2M), f2 (2M) — contiguous.
__global__ __launch_bounds__(256) void convert_layer_sw_k(
    const float* __restrict__ q, const float* __restrict__ k,
    const float* __restrict__ v, const float* __restrict__ o,
    const float* __restrict__ f1, const float* __restrict__ f2,
    const float* __restrict__ qb, const float* __restrict__ kb,
    const float* __restrict__ vb,
    unsigned short* __restrict__ dst, float* __restrict__ bqkv)
{
    if (blockIdx.x >= 8192) {   // bias concat: 12 blocks, 3072 elements
        int i = (blockIdx.x - 8192) * 256 + threadIdx.x;
        float x = (i < 1024) ? qb[i] * 0.125f
                             : ((i < 2048) ? kb[i - 1024] : vb[i - 2048]);
        bqkv[i] = x;
        return;
    }
    int idx = blockIdx.x * 256 + threadIdx.x;   // float4 index, [0, 2M)
    const float* src;
    unsigned short* db;
    int Ksh, rf;
    if (idx < 0x100000) {
        int region = idx >> 18;
        rf = idx & 0x3FFFF;
        src = (region == 0) ? q : (region == 1) ? k : (region == 2) ? v : o;
        db = dst + ((long long)region << 20);
        Ksh = 10;
    } else if (idx < 0x180000) {
        rf = idx - 0x100000; src = f1; db = dst + (4LL << 20); Ksh = 10;
    } else {
        rf = idx - 0x180000; src = f2; db = dst + (6LL << 20); Ksh = 11;
    }
    float4 vv = ((const float4*)src)[rf];
    if (idx < 0x40000) {        // q region: fold the 1/sqrt(64) attn scale
        vv.x *= 0.125f; vv.y *= 0.125f; vv.z *= 0.125f; vv.w *= 0.125f;
    }
    int flatf = rf << 2;
    int n  = flatf >> Ksh;
    int k0 = flatf & ((1 << Ksh) - 1);
    ushort4 ov;
    ov.x = f2bfu(vv.x); ov.y = f2bfu(vv.y); ov.z = f2bfu(vv.z); ov.w = f2bfu(vv.w);
    *(ushort4*)(db + swidx(n, k0, 1 << (Ksh - 5))) = ov;
}

// meanpool partial pass: 256 blocks, 16 rows each, all 1024 d.
__global__ __launch_bounds__(256) void meanpool_part_k(
    const float* __restrict__ h, float* __restrict__ part)
{
    int g = blockIdx.x;                 // g = b*64 + rblk
    int b = g >> 6, rblk = g & 63;
    const float4* base = (const float4*)(h + ((long long)b << 20)
                                           + ((long long)(rblk * 16) << 10));
    float4 s = {0.f, 0.f, 0.f, 0.f};
#pragma unroll
    for (int i = 0; i < 16; i++) {
        float4 v = base[i * 256 + threadIdx.x];
        s.x += v.x; s.y += v.y; s.z += v.z; s.w += v.w;
    }
    ((float4*)part)[g * 256 + threadIdx.x] = s;
}

// final reduce + fc in one kernel: reads meanpool partials directly.
__global__ __launch_bounds__(256) void fc_k(
    const float* __restrict__ part, const float* __restrict__ w,
    const float* __restrict__ fb, float* __restrict__ out)
{
    int b = blockIdx.x, t = threadIdx.x;
    float s = 0.f;
    for (int d = t; d < 1024; d += 256) {
        const float* p = part + (((long long)(b * 64)) << 10) + d;
        float acc = 0.f;
#pragma unroll 8
        for (int r = 0; r < 64; r++) acc += p[r << 10];
        s += acc * w[d];
    }
#pragma unroll
    for (int o = 32; o; o >>= 1) s += __shfl_down(s, o);
    __shared__ float red[4];
    if ((t & 63) == 0) red[t >> 6] = s;
    __syncthreads();
    if (t == 0)
        out[b] = (red[0] + red[1] + red[2] + red[3]) * (1.0f / 1024.0f) + fb[0];
}

// ---------------------------------------------------------------------------
extern "C" void kernel_launch(void* const* d_in, const int* in_sizes, int n_in,
                              void* d_out, int out_size, void* d_ws, size_t ws_size,
                              hipStream_t stream)
{
    const float* x    = (const float*)d_in[0];
    const float* c1w  = (const float*)d_in[1];
    const float* c1b  = (const float*)d_in[2];
    const float* c2w  = (const float*)d_in[3];
    const float* c2b  = (const float*)d_in[4];
    const float* lnAw = (const float*)d_in[5];
    const float* lnAb = (const float*)d_in[6];
    const float* qw   = (const float*)d_in[7];
    const float* qbi  = (const float*)d_in[8];
    const float* kw   = (const float*)d_in[9];
    const float* kbi  = (const float*)d_in[10];
    const float* vw   = (const float*)d_in[11];
    const float* vbi  = (const float*)d_in[12];
    const float* ow   = (const float*)d_in[13];
    const float* obi  = (const float*)d_in[14];
    const float* lnBw = (const float*)d_in[15];
    const float* lnBb = (const float*)d_in[16];
    const float* f1w  = (const float*)d_in[17];
    const float* f1b  = (const float*)d_in[18];
    const float* f2w  = (const float*)d_in[19];
    const float* f2b  = (const float*)d_in[20];
    const float* fcw  = (const float*)d_in[21];
    const float* fcb  = (const float*)d_in[22];
    float* out = (float*)d_out;

    float* ws = (float*)d_ws;
    typedef __hip_bfloat16 bf;
    typedef unsigned short us;
    float* h    = ws;                          // 4,194,304 f
    us* hn_b    = (us*)(ws + 4194304);         // 4M us (swizzled activations)
    us* qkv_b   = (us*)(ws + 6291456);         // [4096][3072] us row-major
    us* ff_b    = qkv_b;                       // [4096][2048] swizzled overlay
    us* h1sw    = qkv_b;                       // conv2 A swizzled (pre-loop)
    us* wq_b    = (us*)(ws + 12582912);        // swizzled: q,k,v,o,f1,f2
    us* wo_b    = (us*)(ws + 14155776);
    us* wf1_b   = (us*)(ws + 14680064);
    us* wf2_b   = (us*)(ws + 15728640);
    us* xb      = (us*)(ws + 16777216);
    us* h1b     = (us*)(ws + 16912896);
    us* w1t_b   = (us*)(ws + 17963520);
    us* w2t_b   = (us*)(ws + 18012672);        // conv2 W swizzled (kt=48)
    us* Vt      = (us*)(ws + 18803200);        // [4][1024 d][1024 t] us
    float* bqkv = ws + 20900352;               // 3,072 f
    float* pe_tab  = ws + 20903424;            // 1,048,576 f (dead after conv2)
    float* mp_part = ws + 20903424;            // 262,144 f (overlays pe_tab)

    convert_k<<<dim3(257), 256, 0, stream>>>(x, xb, 65792);
    reorder_all_w_k<<<dim3(6528), 256, 0, stream>>>(c1w, c2w, w1t_b, w2t_b);
    pe_init_k<<<dim3(4096), 256, 0, stream>>>(pe_tab);

    // conv1: M=4104, N=512, K=192 (LDS-staged kernel, row-remapped A)
    gemm_mfma_k<<<dim3(8, 33), 256, 0, stream>>>(
        (const bf*)xb, 1026, 1028LL * 64, 64, (const bf*)w1t_b,
        c1b, nullptr, nullptr, (bf*)h1b, 4104, 512, 192, 512, 0);
    // conv2 A: im2col rows are contiguous in h1b -> swizzle copy (kt=48)
    convert_h1_sw_k<<<dim3(3072), 256, 0, stream>>>(h1b, h1sw);
    // conv2: M=4096, N=1024, K=1536 on the fast swizzled GEMM, pe fused
    gemm_sw_k<<<dim3(16, 64), 64, 0, stream>>>(
        h1sw, w2t_b, c2b, pe_tab, h, nullptr, nullptr, nullptr, 0,
        4096, 1024, 1536, 1024, 0, 1);

    for (int l = 0; l < 4; l++) {
        long long wo  = (long long)l * 1048576;
        long long wo2 = (long long)l * 2097152;
        convert_layer_sw_k<<<dim3(8204), 256, 0, stream>>>(
            qw + wo, kw + wo, vw + wo, ow + wo, f1w + wo2, f2w + wo2,
            qbi + l * 1024, kbi + l * 1024, vbi + l * 1024, wq_b, bqkv);

        layernorm_k<<<dim3(4096), 256, 0, stream>>>(h, lnAw + l * 1024, lnAb + l * 1024, hn_b);
        // fused QKV: N=3072; Q,K swizzled to qkv_b; V transposed to Vt
        gemm_sw_k<<<dim3(48, 64), 64, 0, stream>>>(
            hn_b, wq_b, bqkv, nullptr, nullptr, qkv_b, nullptr, Vt, 2048,
            4096, 3072, 1024, 3072, 0, 0);
        attn_mfma_k<<<dim3(8, 64), 256, 0, stream>>>(qkv_b, Vt, hn_b);
        // O-proj: out fp32 h += res
        gemm_sw_k<<<dim3(16, 64), 64, 0, stream>>>(
            hn_b, wo_b, obi + l * 1024, h, h, nullptr, nullptr, nullptr, 0,
            4096, 1024, 1024, 1024, 0, 0);
        layernorm_k<<<dim3(4096), 256, 0, stream>>>(h, lnBw + l * 1024, lnBb + l * 1024, hn_b);
        // FF1: out swizzled bf16 (+relu)
        gemm_sw_k<<<dim3(32, 64), 64, 0, stream>>>(
            hn_b, wf1_b, f1b + l * 2048, nullptr, nullptr, nullptr, ff_b, nullptr, 0,
            4096, 2048, 1024, 2048, 1, 0);
        // FF2: out fp32 h += res
        gemm_sw_k<<<dim3(16, 64), 64, 0, stream>>>(
            ff_b, wf2_b, f2b + l * 1024, h, h, nullptr, nullptr, nullptr, 0,
            4096, 1024, 2048, 1024, 0, 0);
    }

    meanpool_part_k<<<dim3(256), 256, 0, stream>>>(h, mp_part);
    fc_k<<<dim3(4), 256, 0, stream>>>(mp_part, fcw, fcb, out);
}